// Round 18
// baseline (259.305 us; speedup 1.0000x reference)
//
#include <hip/hip_runtime.h>
#include <math.h>

#define WW 64
#define HH 64
#define L 4096
#define NC 64
#define D3 576
#define ASCALE (1.0f/128.0f)
#define QB 32
#define NSPLIT 4          // key-slices per z; 4 waves each -> 16 partial sets per z
#define D9W 2200          // staged cols per row-half (2192 used + pad)

typedef _Float16 f16x8 __attribute__((ext_vector_type(8)));
typedef _Float16 f16x4 __attribute__((ext_vector_type(4)));
typedef float    f32x4 __attribute__((ext_vector_type(4)));

__device__ __forceinline__ float wave_max(float v){
  #pragma unroll
  for(int o=32;o;o>>=1) v = fmaxf(v, __shfl_xor(v,o));
  return v;
}
__device__ __forceinline__ float wave_sum(float v){
  #pragma unroll
  for(int o=32;o;o>>=1) v += __shfl_xor(v,o);
  return v;
}
__device__ __forceinline__ void gload16(const void* g, void* l){
  __builtin_amdgcn_global_load_lds((const __attribute__((address_space(1))) unsigned int*)g,
                                   (__attribute__((address_space(3))) unsigned int*)l,
                                   16, 0, 0);
}

// ---------------- fused: fg transpose + bgH build ----------------
__global__ __launch_bounds__(256) void prep_fg(const float* __restrict__ fg,
                                               const float* __restrict__ mask,
                                               float* __restrict__ fgT,
                                               _Float16* __restrict__ bgH){
  __shared__ float tile[64][65];
  __shared__ float msh[64];
  const int z = blockIdx.y;
  const int q0 = blockIdx.x*64;
  const int tx = threadIdx.x & 63, ty = threadIdx.x >> 6;
  if(threadIdx.x < 64) msh[threadIdx.x] = mask[(size_t)z*L + q0 + threadIdx.x];
  #pragma unroll
  for(int i=0;i<16;i++){
    const int c = ty*16 + i;
    tile[c][tx] = fg[((size_t)z*64 + c)*L + q0 + tx];
  }
  __syncthreads();
  #pragma unroll
  for(int i=0;i<16;i++){
    const int q = ty*16 + i;
    fgT[((size_t)z*L + q0 + q)*64 + tx] = tile[tx][q];
  }
  const float mval = (1.0f - msh[tx])*128.0f;
  #pragma unroll
  for(int i=0;i<16;i++){
    const int c = ty*16 + i;
    bgH[((size_t)z*128 + c)*L + q0 + tx] = (_Float16)(tile[c][tx]*mval);
    bgH[((size_t)z*128 + 64 + c)*L + q0 + tx] = (_Float16)0.f;
  }
}

// ---------------- fused builder: p1 (Bhat,Pfg) + p3 (Bhat,rn3,PfgBox) ----------------
__global__ __launch_bounds__(256) void build_all(const float* __restrict__ fgT,
                                                 const float* __restrict__ mask,
                                                 _Float16* __restrict__ BhatH1,
                                                 _Float16* __restrict__ PfgH1,
                                                 _Float16* __restrict__ BhatH3,
                                                 _Float16* __restrict__ PfgH3,
                                                 float* __restrict__ rn3){
  const int t = threadIdx.x, c = t & 63, sub = t >> 6;
  const int l = blockIdx.x*4 + sub, z = blockIdx.y;
  const float* fgz = fgT + (size_t)z*L*64;
  const float* mz  = mask + (size_t)z*L;
  const int y = l >> 6, x = l & 63;
  float Wn[5][5];
  #pragma unroll
  for(int u=0;u<5;u++){
    const int yy = y+u-2;
    #pragma unroll
    for(int v=0;v<5;v++){
      const int xx = x+v-2;
      Wn[u][v] = (yy>=0 && yy<HH && xx>=0 && xx<WW) ? fgz[(size_t)(yy*WW+xx)*64 + c] : 0.f;
    }
  }
  float m3[3][3];
  #pragma unroll
  for(int i=0;i<3;i++){
    #pragma unroll
    for(int j=0;j<3;j++){
      const int yy = y+i-1, xx = x+j-1;
      m3[i][j] = (yy>=0&&yy<HH&&xx>=0&&xx<WW) ? mz[yy*WW+xx] : 0.f;
    }
  }
  // ---- p1 ----
  {
    const float K1 = Wn[2][2]*(1.0f - m3[1][1]) + 1e-7f;
    const float ss = wave_sum(K1*K1);
    BhatH1[((size_t)z*L + l)*NC + c] = (_Float16)(K1*rsqrtf(ss));
    float s = 0.f;
    #pragma unroll
    for(int a=0;a<3;a++)
      #pragma unroll
      for(int b=0;b<3;b++) s += Wn[1+a][1+b];
    PfgH1[((size_t)z*L + l)*NC + c] = (_Float16)s;
  }
  // ---- p3 Bhat + rn3 ----
  {
    float K[9]; float ss = 0.f;
    #pragma unroll
    for(int i=0;i<3;i++)
      #pragma unroll
      for(int j=0;j<3;j++){
        const float v = Wn[1+i][1+j]*(1.0f - m3[i][j]) + 1e-7f;
        K[i*3+j] = v; ss += v*v;
      }
    ss = wave_sum(ss);
    const float rn = rsqrtf(ss);
    _Float16* outp = BhatH3 + ((size_t)z*L + l)*D3 + c*9;
    #pragma unroll
    for(int k=0;k<9;k++) outp[k] = (_Float16)(K[k]*rn);
    if(c==0) rn3[(size_t)z*L + l] = rn;
  }
  // ---- p3 PfgBox ----
  {
    const bool dyok[3] = { y-1>=0, true, y+1<HH };
    const bool dxok[3] = { x-1>=0, true, x+1<WW };
    _Float16* outp = PfgH3 + ((size_t)z*L + l)*D3 + c*9;
    #pragma unroll
    for(int i=0;i<3;i++)
      #pragma unroll
      for(int j=0;j<3;j++){
        float acc = 0.f;
        #pragma unroll
        for(int a=0;a<3;a++){
          if(!dyok[a]) continue;
          #pragma unroll
          for(int b=0;b<3;b++){
            if(!dxok[b]) continue;
            acc += Wn[i+a][j+b];
          }
        }
        outp[i*3+j] = (_Float16)acc;
      }
  }
}

__global__ __launch_bounds__(256) void transpose_h(const ushort* __restrict__ src,
                                                   ushort* __restrict__ dst,
                                                   int C, size_t sSz, size_t sDz){
  __shared__ ushort tile[64][65];
  const int z = blockIdx.z;
  src += z*sSz; dst += z*sDz;
  const int bc = blockIdx.x*64, br = blockIdx.y*64;
  const int tx = threadIdx.x & 15, ty = threadIdx.x >> 4;
  #pragma unroll
  for(int i=0;i<4;i++){
    const ushort4 v = *(const ushort4*)(src + (size_t)(br+ty+16*i)*C + bc + tx*4);
    tile[ty+16*i][tx*4+0] = v.x;
    tile[ty+16*i][tx*4+1] = v.y;
    tile[ty+16*i][tx*4+2] = v.z;
    tile[ty+16*i][tx*4+3] = v.w;
  }
  __syncthreads();
  #pragma unroll
  for(int i=0;i<4;i++){
    ushort4 o;
    o.x = tile[tx*4+0][ty+16*i];
    o.y = tile[tx*4+1][ty+16*i];
    o.z = tile[tx*4+2][ty+16*i];
    o.w = tile[tx*4+3][ty+16*i];
    *(ushort4*)(dst + (size_t)(bc+ty+16*i)*L + br + tx*4) = o;
  }
}

// ---------------- barrier-free per-wave flash attention (p=1) ----------------
__global__ __launch_bounds__(256) void flash_p1(const _Float16* __restrict__ Q,
                                                const _Float16* __restrict__ Km,
                                                const _Float16* __restrict__ Vt,
                                                float* __restrict__ Op,
                                                float* __restrict__ Ml,
                                                float* __restrict__ Ll){
  __shared__ _Float16 Qs[QB*64];
  __shared__ _Float16 KsA[4][QB*64];
  __shared__ _Float16 VsA[4][64*32];
  __shared__ _Float16 PsA[4][QB*32];
  __shared__ float    FwA[4][QB];
  const int z = blockIdx.z, sp = blockIdx.y, q0 = blockIdx.x*QB;
  const int t = threadIdx.x, lane = t&63, wave = t>>6;
  const int r16 = lane&15, g4 = lane>>4;
  _Float16* Ks = KsA[wave];
  _Float16* Vs = VsA[wave];
  _Float16* Ps = PsA[wave];
  float* Fw = FwA[wave];
  {
    const int row = t>>3, ch = t&7;
    gload16(Q + ((size_t)z*L + q0 + row)*64 + ((ch ^ (row&7))<<3), (char*)Qs + t*16);
  }
  asm volatile("s_waitcnt vmcnt(0)" ::: "memory");
  __syncthreads();

  float Mreg[2] = {-3.0e38f, -3.0e38f};
  float Lreg[2] = {0.f, 0.f};
  f32x4 accO[2][4] = {};

  for(int tt=0; tt<8; ++tt){
    const int lbase = sp*1024 + tt*128 + wave*32;
    #pragma unroll
    for(int u=0;u<4;u++){
      const int row = u*8 + (lane>>3), ch = lane&7;
      gload16(Km + ((size_t)z*L + lbase + row)*64 + ((ch ^ (row&7))<<3),
              (char*)Ks + u*1024 + lane*16);
    }
    #pragma unroll
    for(int u=0;u<4;u++){
      const int cst = u*16 + (lane>>2), slot = lane&3;
      gload16(Vt + ((size_t)z*64 + cst)*L + lbase + ((slot ^ (cst&3))<<3),
              (char*)Vs + u*1024 + lane*16);
    }
    asm volatile("s_waitcnt vmcnt(0)" ::: "memory");
    __builtin_amdgcn_sched_barrier(0);
    f32x4 acc[2][2] = {};
    #pragma unroll
    for(int kk=0;kk<2;kk++){
      f16x8 af[2], bf[2];
      #pragma unroll
      for(int i=0;i<2;i++){
        const int row = i*16 + r16;
        af[i] = *(const f16x8*)((const char*)Ks + (((row<<7) + kk*64 + (g4<<4)) ^ ((row&7)<<4)));
      }
      #pragma unroll
      for(int j=0;j<2;j++){
        const int row = j*16 + r16;
        bf[j] = *(const f16x8*)((const char*)Qs + (((row<<7) + kk*64 + (g4<<4)) ^ ((row&7)<<4)));
      }
      #pragma unroll
      for(int i=0;i<2;i++)
        #pragma unroll
        for(int j=0;j<2;j++)
          acc[i][j] = __builtin_amdgcn_mfma_f32_16x16x32_f16(af[i], bf[j], acc[i][j], 0,0,0);
    }
    float fs[2];
    #pragma unroll
    for(int j=0;j<2;j++){
      float mv = -3.0e38f;
      #pragma unroll
      for(int i=0;i<2;i++)
        #pragma unroll
        for(int r=0;r<4;r++) mv = fmaxf(mv, acc[i][j][r]);
      mv = fmaxf(mv, __shfl_xor(mv, 16));
      mv = fmaxf(mv, __shfl_xor(mv, 32));
      const float mnew = fmaxf(Mreg[j], mv);
      fs[j] = __expf(Mreg[j] - mnew);
      Mreg[j] = mnew;
      float ps = 0.f;
      const int q = j*16 + r16;
      #pragma unroll
      for(int i=0;i<2;i++){
        f16x4 ph;
        #pragma unroll
        for(int r=0;r<4;r++){
          const float p = __expf(acc[i][j][r] - mnew);
          ps += p; ph[r] = (_Float16)p;
        }
        *(f16x4*)((char*)Ps + (q<<6) + ((i*32 + g4*8) ^ ((q&3)<<4))) = ph;
      }
      ps += __shfl_xor(ps, 16);
      ps += __shfl_xor(ps, 32);
      Lreg[j] = Lreg[j]*fs[j] + ps;
    }
    if(g4==0){ Fw[r16] = fs[0]; Fw[16+r16] = fs[1]; }
    #pragma unroll
    for(int qb=0;qb<2;qb++){
      float f4[4];
      #pragma unroll
      for(int r=0;r<4;r++) f4[r] = Fw[qb*16 + g4*4 + r];
      #pragma unroll
      for(int cb=0;cb<4;cb++)
        #pragma unroll
        for(int r=0;r<4;r++) accO[qb][cb][r] *= f4[r];
    }
    #pragma unroll
    for(int qb=0;qb<2;qb++){
      const int qrow = qb*16 + r16;
      const f16x8 af = *(const f16x8*)((const char*)Ps + (qrow<<6) + ((g4<<4) ^ ((qrow&3)<<4)));
      #pragma unroll
      for(int cb=0;cb<4;cb++){
        const int crow = cb*16 + r16;
        const f16x8 bf = *(const f16x8*)((const char*)Vs + (crow<<6) + ((g4<<4) ^ ((crow&3)<<4)));
        accO[qb][cb] = __builtin_amdgcn_mfma_f32_16x16x32_f16(af, bf, accO[qb][cb], 0,0,0);
      }
    }
  }
  const int sidx = (z*NSPLIT + sp)*4 + wave;
  #pragma unroll
  for(int qb=0;qb<2;qb++){
    #pragma unroll
    for(int cb=0;cb<4;cb++){
      #pragma unroll
      for(int r=0;r<4;r++){
        const int ql = qb*16 + g4*4 + r;
        Op[((size_t)sidx*L + q0 + ql)*64 + cb*16 + r16] = accO[qb][cb][r];
      }
    }
  }
  if(g4==0){
    Ml[(size_t)sidx*L + q0 + r16]      = Mreg[0];
    Ml[(size_t)sidx*L + q0 + 16 + r16] = Mreg[1];
    Ll[(size_t)sidx*L + q0 + r16]      = Lreg[0];
    Ll[(size_t)sidx*L + q0 + 16 + r16] = Lreg[1];
  }
}

// OM=2: fp16 output (KS=1), 2D XCD-region swizzle; OM=3: fp16 split-K partials.
// __launch_bounds__(256,3): request 3 waves/EU (= 3 blocks/CU) — VGPR budget 148 <= 170.
template<int OM, int KS>
__global__ __launch_bounds__(256, 3) void gemm_h16(const _Float16* __restrict__ A, int lda, size_t sAz,
                                                   const _Float16* __restrict__ B, int ldb, size_t sBz,
                                                   void* __restrict__ C, int ldc, size_t sCz,
                                                   int K, size_t sPart){
  __shared__ _Float16 sh[16384];   // As(8192) + Bs(8192) = 32768 B total
  _Float16* As = sh;
  _Float16* Bs = sh + 8192;
  const int zz = blockIdx.z;
  const int z = zz / KS, ks = zz % KS;
  const int Kp = K / KS;
  A += (size_t)z*sAz + (size_t)ks*Kp;
  B += (size_t)z*sBz + (size_t)ks*Kp;
  int bxi = blockIdx.x, byi = blockIdx.y;
  if(OM==2){
    // 2D XCD-region swizzle over the 32x32 tile plane: each XCD (dispatch i%8)
    // owns an 8(bm) x 16(bn) region -> per-XCD working set A 1.18MB + B 2.36MB < 4MB L2.
    const int i = byi*32 + bxi;           // dispatch-linear within this z
    const int xcd = i & 7, tt = (i >> 3) & 127;
    byi = 8*(xcd & 3) + (tt & 7);
    bxi = 16*(xcd >> 2) + (tt >> 3);
  }
  const int bm = byi*128, bn = bxi*128;
  const int t = threadIdx.x, lane = t & 63, wave = t >> 6;
  const int wr = wave >> 1, wc = wave & 1;
  const int r16 = lane & 15, g4 = lane >> 4;
  const int srow = t >> 3;
  const int schunk = t & 7;
  f32x4 acc[4][4] = {};
  for(int k0=0;k0<Kp;k0+=64){
    #pragma unroll
    for(int u=0;u<4;u++){
      const int rowA = u*32 + srow;
      const int colh = ((schunk ^ (rowA & 7)) << 3);
      gload16(A + (size_t)(bm+rowA)*lda + k0 + colh, (char*)As + u*4096 + wave*1024);
      gload16(B + (size_t)(bn+rowA)*ldb + k0 + colh, (char*)Bs + u*4096 + wave*1024);
    }
    __syncthreads();
    #pragma unroll
    for(int kk=0;kk<2;kk++){
      f16x8 af[4], bf[4];
      #pragma unroll
      for(int i=0;i<4;i++){
        const int row = wr*64 + i*16 + r16;
        const int off = ((row<<7) + kk*64 + (g4<<4)) ^ ((row&7)<<4);
        af[i] = *(const f16x8*)((const char*)As + off);
      }
      #pragma unroll
      for(int j=0;j<4;j++){
        const int row = wc*64 + j*16 + r16;
        const int off = ((row<<7) + kk*64 + (g4<<4)) ^ ((row&7)<<4);
        bf[j] = *(const f16x8*)((const char*)Bs + off);
      }
      #pragma unroll
      for(int i=0;i<4;i++)
        #pragma unroll
        for(int j=0;j<4;j++)
          acc[i][j] = __builtin_amdgcn_mfma_f32_16x16x32_f16(af[i], bf[j], acc[i][j], 0, 0, 0);
    }
    __syncthreads();
  }
  // two-half LDS-transpose fp16 epilogue (reuses As/Bs space)
  _Float16* Cz = (_Float16*)C + (OM==2 ? (size_t)z*sCz
                                       : (size_t)ks*sPart + (size_t)z*sCz);
  #pragma unroll
  for(int h=0; h<2; ++h){
    __syncthreads();
    if(wr == h){
      #pragma unroll
      for(int i=0;i<4;i++){
        const int row0 = i*16 + g4*4;
        #pragma unroll
        for(int j=0;j<4;j++){
          const int col = wc*64 + j*16 + r16;
          #pragma unroll
          for(int r=0;r<4;r++)
            sh[(row0+r)*136 + col] = (_Float16)acc[i][j][r];
        }
      }
    }
    __syncthreads();
    #pragma unroll
    for(int k=0;k<4;k++){
      const int row = k*16 + (t>>4);
      const int cg = (t&15)*8;
      const f16x8 v = *(const f16x8*)(sh + row*136 + cg);
      *(f16x8*)(Cz + (size_t)(bm + h*64 + row)*ldc + bn + cg) = v;
    }
  }
}

__global__ __launch_bounds__(256) void softmax_rn(_Float16* __restrict__ S,
                                                  const float* __restrict__ rn3,
                                                  float* __restrict__ Tq){
  __shared__ float red[4];
  const int q = blockIdx.x, z = blockIdx.y, t = threadIdx.x;
  _Float16* p = S + ((size_t)z*L + q)*L;
  float v[16];
  {
    const f16x8 a = *(const f16x8*)(p + t*16);
    const f16x8 b = *(const f16x8*)(p + t*16 + 8);
    #pragma unroll
    for(int i=0;i<8;i++){ v[i] = (float)a[i]; v[8+i] = (float)b[i]; }
  }
  float mx = -3.0e38f;
  #pragma unroll
  for(int i=0;i<16;i++) mx = fmaxf(mx, v[i]);
  mx = wave_max(mx);
  if((t&63)==0) red[t>>6]=mx;
  __syncthreads();
  mx = fmaxf(fmaxf(red[0],red[1]), fmaxf(red[2],red[3]));
  __syncthreads();
  float s = 0.f;
  #pragma unroll
  for(int i=0;i<16;i++){ v[i] = __expf(v[i]-mx); s += v[i]; }
  s = wave_sum(s);
  if((t&63)==0) red[t>>6]=s;
  __syncthreads();
  s = red[0]+red[1]+red[2]+red[3];
  __syncthreads();
  const float inv = 1.0f/s;
  const float* rnz = rn3 + (size_t)z*L + t*16;
  float T = 0.f;
  f16x8 a, b;
  #pragma unroll
  for(int i=0;i<8;i++){
    const float w0 = v[i]*inv*rnz[i];
    const float w1 = v[8+i]*inv*rnz[8+i];
    T += w0 + w1;
    a[i] = (_Float16)(w0*ASCALE);
    b[i] = (_Float16)(w1*ASCALE);
  }
  *(f16x8*)(p + t*16) = a;
  *(f16x8*)(p + t*16 + 8) = b;
  T = wave_sum(T);
  if((t&63)==0) red[t>>6]=T;
  __syncthreads();
  if(t==0) Tq[(size_t)z*L + q] = red[0]+red[1]+red[2]+red[3];
}

// ---------------- 9-tap diagonal stencil, half-width staged ----------------
__global__ __launch_bounds__(256) void d9_pass(const _Float16* __restrict__ in,
                                               _Float16* __restrict__ out){
  __shared__ _Float16 rows[9*D9W];
  const int bx = blockIdx.x, by = blockIdx.y, t = threadIdx.x;
  const int a = (bx&7)*512 + (bx>>3);
  const int z = by & 1, h = by >> 1;
  const int cbase = h*2048 - 72;
  const int ya = a>>6, xa = a&63;
  const int DY[9] = {-1,-1,-1, 0,0,0, 1,1,1};
  const int DX[9] = {-1, 0, 1,-1,0,1,-1,0,1};
  bool vr[9];
  #pragma unroll
  for(int k=0;k<9;k++){
    const int yy = ya + DY[k], xx = xa + DX[k];
    vr[k] = (yy>=0 && yy<64 && xx>=0 && xx<64);
    if(vr[k]){
      const _Float16* src = in + ((size_t)z*L + a + DY[k]*64 + DX[k])*L;
      int g0 = cbase + t*8;
      g0 = g0 < 0 ? 0 : g0;
      gload16(src + g0, (char*)rows + k*(D9W*2) + t*16);
      const int g1 = cbase + (256+t)*8;
      if(t < 18 && g1 < L)
        gload16(src + g1, (char*)rows + k*(D9W*2) + 4096 + t*16);
    }
  }
  __syncthreads();
  const int m0 = h*2048 + t*8;
  const int ym = m0>>6, x0 = m0&63;
  float o[8] = {0,0,0,0,0,0,0,0};
  #pragma unroll
  for(int k=0;k<9;k++){
    const int D = DY[k]*64 + DX[k];
    const bool vy = vr[k] && ((unsigned)(ym + DY[k]) < 64u);
    if(!vy) continue;
    const int r = ((D % 8) + 8) % 8;
    const int loff = t*8 + 72 + D - r;
    const _Float16* p = rows + k*D9W + loff;
    _Float16 buf[16];
    *(f16x8*)(buf)   = *(const f16x8*)(p);
    *(f16x8*)(buf+8) = *(const f16x8*)(p+8);
    #pragma unroll
    for(int i=0;i<8;i++){
      const bool vx = (unsigned)(x0 + i + DX[k]) < 64u;
      o[i] += vx ? (float)buf[r + i] : 0.f;
    }
  }
  f16x8 w0;
  #pragma unroll
  for(int i=0;i<8;i++) w0[i] = (_Float16)o[i];
  *(f16x8*)(out + ((size_t)z*L + a)*L + m0) = w0;
}

// ---------------- fused epilogue: flash combine + p3 scatter + SE partials ----------
__global__ __launch_bounds__(256) void epilogue_qc(const float* __restrict__ Op,
                                                   const float* __restrict__ Ml,
                                                   const float* __restrict__ Ll,
                                                   const _Float16* __restrict__ Cp,
                                                   const float* __restrict__ Tq,
                                                   const float* __restrict__ fgT,
                                                   const float* __restrict__ mask,
                                                   float* __restrict__ outs,
                                                   float* __restrict__ part,
                                                   size_t sPart){
  __shared__ float ps[4][128];
  const int z = blockIdx.y, t = threadIdx.x;
  const int sub = t >> 6;
  const int q = blockIdx.x*4 + sub, c = t & 63;
  const float m = mask[(size_t)z*L + q];
  const float f = fgT[((size_t)z*L + q)*64 + c];
  float o1, o3;
  // ---- p1: combine 16 raw fp32 flash partial sets ----
  {
    float mv[16];
    float ms = -3.0e38f;
    #pragma unroll
    for(int s=0;s<16;s++){
      mv[s] = Ml[(size_t)(z*16+s)*L + q];
      ms = fmaxf(ms, mv[s]);
    }
    float acc = 0.f, Lt = 0.f;
    #pragma unroll
    for(int s=0;s<16;s++){
      const float w0 = __expf(mv[s] - ms);
      acc += w0 * Op[((size_t)(z*16+s)*L + q)*64 + c];
      Lt  += w0 * Ll[(size_t)(z*16+s)*L + q];
    }
    const float o = acc/Lt;
    o1 = o*m + f*(1.0f-m);
    outs[((size_t)z*L + q)*128 + c] = o1;
  }
  // ---- p3: split-K reduce + eps + mask mix ----
  {
    const int y = q >> 6, x = q & 63;
    const size_t idx = ((size_t)z*L + q)*128 + c;
    float rec = 0.f;
    #pragma unroll
    for(int k=0;k<8;k++) rec += (float)Cp[(size_t)k*sPart + idx];
    float tb = 0.f;
    #pragma unroll
    for(int dy=-1;dy<=1;dy++){
      const int yy = y+dy;
      if(yy<0||yy>=64) continue;
      #pragma unroll
      for(int dx=-1;dx<=1;dx++){
        const int xx = x+dx;
        if(xx<0||xx>=64) continue;
        tb += Tq[(size_t)z*L + yy*64+xx];
      }
    }
    rec += 1e-7f*tb;
    o3 = rec*(m*(1.0f/9.0f)) + f*(1.0f-m);
    outs[((size_t)z*L + q)*128 + 64 + c] = o3;
  }
  // ---- SE channel partials ----
  ps[sub][c] = o1;
  ps[sub][64 + c] = o3;
  __syncthreads();
  if(t < 128){
    const float s = ps[0][t] + ps[1][t] + ps[2][t] + ps[3][t];
    part[((size_t)z*1024 + blockIdx.x)*128 + t] = s;
  }
}

// ---------------- SE MLP (512 threads) ----------------
__global__ __launch_bounds__(512) void se_mlp(const float* __restrict__ part,
                                              const float* __restrict__ W1, const float* __restrict__ b1,
                                              const float* __restrict__ W2, const float* __restrict__ b2,
                                              float* __restrict__ g){
  __shared__ float red[4][128];
  __shared__ float s[128], h[128];
  const int z = blockIdx.x, t = threadIdx.x;
  const int ch = t & 127, sl = t >> 7;
  float a0 = 0.f;
  for(int j=sl*256; j<(sl+1)*256; ++j)
    a0 += part[((size_t)z*1024 + j)*128 + ch];
  red[sl][ch] = a0;
  __syncthreads();
  if(t < 128) s[t] = (red[0][t]+red[1][t]+red[2][t]+red[3][t])*(1.0f/4096.0f);
  __syncthreads();
  if(t < 128){
    float a = b1[t];
    const float* w = W1 + (size_t)t*128;
    for(int j=0;j<128;j++) a = fmaf(w[j], s[j], a);
    h[t] = fmaxf(a, 0.f);
  }
  __syncthreads();
  if(t < 128){
    float o = b2[t];
    const float* w = W2 + (size_t)t*128;
    for(int j=0;j<128;j++) o = fmaf(w[j], h[j], o);
    g[z*128+t] = 1.0f/(1.0f + __expf(-o));
  }
}

// ---------------- combiner 1x1 conv (float4-vectorized inner loop) ----------------
__global__ __launch_bounds__(256) void combiner(const float* __restrict__ outs,
                                                const float* __restrict__ g,
                                                const float* __restrict__ Wc,
                                                const float* __restrict__ bc,
                                                float* __restrict__ out){
  const size_t idx = (size_t)blockIdx.x*256 + threadIdx.x;
  const int q = (int)(idx & 4095);
  const int o = (int)((idx >> 12) & 63);
  const int z = (int)(idx >> 18);
  const float4* ob4 = (const float4*)(outs + ((size_t)z*L + q)*128);
  const float4* gz4 = (const float4*)(g + z*128);
  const float4* wr4 = (const float4*)(Wc + (size_t)o*128);
  float acc = bc[o];
  #pragma unroll 8
  for(int ch=0; ch<32; ++ch){
    const float4 a = ob4[ch], gg = gz4[ch], b = wr4[ch];
    acc = fmaf(a.x*gg.x, b.x, acc);
    acc = fmaf(a.y*gg.y, b.y, acc);
    acc = fmaf(a.z*gg.z, b.z, acc);
    acc = fmaf(a.w*gg.w, b.w, acc);
  }
  out[idx] = acc;
}

extern "C" void kernel_launch(void* const* d_in, const int* in_sizes, int n_in,
                              void* d_out, int out_size, void* d_ws, size_t ws_size,
                              hipStream_t stream){
  const float* fg   = (const float*)d_in[0];
  const float* mask = (const float*)d_in[1];
  const float* W1   = (const float*)d_in[2];
  const float* b1   = (const float*)d_in[3];
  const float* W2   = (const float*)d_in[4];
  const float* b2   = (const float*)d_in[5];
  const float* Wc   = (const float*)d_in[6];
  const float* bc   = (const float*)d_in[7];
  float* out = (float*)d_out;

  char* w = (char*)d_ws;
  size_t off = 0;
  auto alloc = [&](size_t bytes)->void*{
    void* p = (void*)(w + off);
    off += (bytes + 255) & ~(size_t)255;
    return p;
  };
  _Float16* S    = (_Float16*)alloc(2ull*L*L*2);   // p3 scores / A''
  _Float16* DxB  = (_Float16*)alloc(2ull*L*L*2);   // d9 output G
  _Float16* Cp16 = (_Float16*)alloc(8ull*2*L*128*2); // fp16 split-K partials
  float* outs  = (float*)alloc(2ull*L*128*4);
  float* fgT   = (float*)alloc(2ull*L*64*4);
  _Float16* BhatH1 = (_Float16*)alloc(2ull*L*64*2);
  _Float16* BhatT1 = (_Float16*)alloc(2ull*64*L*2);
  _Float16* PfgH1  = (_Float16*)alloc(2ull*L*64*2);
  _Float16* BhatH3 = (_Float16*)alloc(2ull*L*D3*2);
  _Float16* PfgH3  = (_Float16*)alloc(2ull*L*D3*2);
  _Float16* bgH    = (_Float16*)alloc(2ull*128*L*2);
  float* Opb  = (float*)alloc((size_t)32*L*64*4);   // raw fp32 flash partials
  float* Mlb  = (float*)alloc((size_t)32*L*4);
  float* Llb  = (float*)alloc((size_t)32*L*4);
  float* rn3v = (float*)alloc(2ull*L*4);
  float* Tq   = (float*)alloc(2ull*L*4);
  float* part = (float*)alloc(2ull*1024*128*4);
  float* gbuf = (float*)alloc(1024);
  const size_t sPart = 2ull*L*128;   // elements per split (fp16)

  // ================= prep (fused transpose + bgH) =================
  prep_fg<<<dim3(64,2),256,0,stream>>>(fg, mask, fgT, bgH);
  build_all<<<dim3(L/4,2),256,0,stream>>>(fgT, mask, BhatH1, PfgH1, BhatH3, PfgH3, rn3v);
  transpose_h<<<dim3(1,64,2),256,0,stream>>>((const ushort*)BhatH1, (ushort*)BhatT1,
                                             64, (size_t)L*64, (size_t)64*L);

  // ================= p=1 branch (barrier-free flash, 16-way split) =================
  flash_p1<<<dim3(L/QB,NSPLIT,2),256,0,stream>>>(PfgH1, BhatH1, BhatT1, Opb, Mlb, Llb);

  // ================= p=3 branch =================
  gemm_h16<2,1><<<dim3(32,32,2),256,0,stream>>>(
      PfgH3, D3, (size_t)L*D3,
      BhatH3, D3, (size_t)L*D3,
      (void*)S, L, (size_t)L*L, D3, 0);
  softmax_rn<<<dim3(L,2),256,0,stream>>>(S, rn3v, Tq);
  d9_pass<<<dim3(L,4),256,0,stream>>>(S, DxB);
  gemm_h16<3,8><<<dim3(1,32,16),256,0,stream>>>(
      DxB, L, (size_t)L*L,
      bgH, L, (size_t)128*L,
      (void*)Cp16, 128, (size_t)L*128, L, sPart);

  // ================= fused epilogue (both branches + SE partials) =================
  epilogue_qc<<<dim3(L/4,2),256,0,stream>>>(Opb, Mlb, Llb, Cp16, Tq, fgT, mask,
                                            outs, part, sPart);

  // ================= SE + combiner =================
  se_mlp<<<2,512,0,stream>>>(part, W1, b1, W2, b2, gbuf);
  combiner<<<(2*64*L)/256,256,0,stream>>>(outs, gbuf, Wc, bc, out);
}

// Round 19
// 224.126 us; speedup vs baseline: 1.1570x; 1.1570x over previous
//
#include <hip/hip_runtime.h>
#include <math.h>

#define WW 64
#define HH 64
#define L 4096
#define NC 64
#define D3 576
#define ASCALE (1.0f/128.0f)
#define QB 32
#define NSPLIT 4          // key-slices per z; 4 waves each -> 16 partial sets per z
#define D9W 2200          // staged cols per row-half (2192 used + pad)

typedef _Float16 f16x8 __attribute__((ext_vector_type(8)));
typedef _Float16 f16x4 __attribute__((ext_vector_type(4)));
typedef float    f32x4 __attribute__((ext_vector_type(4)));

__device__ __forceinline__ float wave_max(float v){
  #pragma unroll
  for(int o=32;o;o>>=1) v = fmaxf(v, __shfl_xor(v,o));
  return v;
}
__device__ __forceinline__ float wave_sum(float v){
  #pragma unroll
  for(int o=32;o;o>>=1) v += __shfl_xor(v,o);
  return v;
}
__device__ __forceinline__ void gload16(const void* g, void* l){
  __builtin_amdgcn_global_load_lds((const __attribute__((address_space(1))) unsigned int*)g,
                                   (__attribute__((address_space(3))) unsigned int*)l,
                                   16, 0, 0);
}

// ---------------- fused: fg transpose + bgH build ----------------
__global__ __launch_bounds__(256) void prep_fg(const float* __restrict__ fg,
                                               const float* __restrict__ mask,
                                               float* __restrict__ fgT,
                                               _Float16* __restrict__ bgH){
  __shared__ float tile[64][65];
  __shared__ float msh[64];
  const int z = blockIdx.y;
  const int q0 = blockIdx.x*64;
  const int tx = threadIdx.x & 63, ty = threadIdx.x >> 6;
  if(threadIdx.x < 64) msh[threadIdx.x] = mask[(size_t)z*L + q0 + threadIdx.x];
  #pragma unroll
  for(int i=0;i<16;i++){
    const int c = ty*16 + i;
    tile[c][tx] = fg[((size_t)z*64 + c)*L + q0 + tx];
  }
  __syncthreads();
  #pragma unroll
  for(int i=0;i<16;i++){
    const int q = ty*16 + i;
    fgT[((size_t)z*L + q0 + q)*64 + tx] = tile[tx][q];
  }
  const float mval = (1.0f - msh[tx])*128.0f;
  #pragma unroll
  for(int i=0;i<16;i++){
    const int c = ty*16 + i;
    bgH[((size_t)z*128 + c)*L + q0 + tx] = (_Float16)(tile[c][tx]*mval);
    bgH[((size_t)z*128 + 64 + c)*L + q0 + tx] = (_Float16)0.f;
  }
}

// ---------------- fused builder: p1 (Bhat,Pfg) + p3 (Bhat,rn3,PfgBox) ----------------
__global__ __launch_bounds__(256) void build_all(const float* __restrict__ fgT,
                                                 const float* __restrict__ mask,
                                                 _Float16* __restrict__ BhatH1,
                                                 _Float16* __restrict__ PfgH1,
                                                 _Float16* __restrict__ BhatH3,
                                                 _Float16* __restrict__ PfgH3,
                                                 float* __restrict__ rn3){
  const int t = threadIdx.x, c = t & 63, sub = t >> 6;
  const int l = blockIdx.x*4 + sub, z = blockIdx.y;
  const float* fgz = fgT + (size_t)z*L*64;
  const float* mz  = mask + (size_t)z*L;
  const int y = l >> 6, x = l & 63;
  float Wn[5][5];
  #pragma unroll
  for(int u=0;u<5;u++){
    const int yy = y+u-2;
    #pragma unroll
    for(int v=0;v<5;v++){
      const int xx = x+v-2;
      Wn[u][v] = (yy>=0 && yy<HH && xx>=0 && xx<WW) ? fgz[(size_t)(yy*WW+xx)*64 + c] : 0.f;
    }
  }
  float m3[3][3];
  #pragma unroll
  for(int i=0;i<3;i++){
    #pragma unroll
    for(int j=0;j<3;j++){
      const int yy = y+i-1, xx = x+j-1;
      m3[i][j] = (yy>=0&&yy<HH&&xx>=0&&xx<WW) ? mz[yy*WW+xx] : 0.f;
    }
  }
  // ---- p1 ----
  {
    const float K1 = Wn[2][2]*(1.0f - m3[1][1]) + 1e-7f;
    const float ss = wave_sum(K1*K1);
    BhatH1[((size_t)z*L + l)*NC + c] = (_Float16)(K1*rsqrtf(ss));
    float s = 0.f;
    #pragma unroll
    for(int a=0;a<3;a++)
      #pragma unroll
      for(int b=0;b<3;b++) s += Wn[1+a][1+b];
    PfgH1[((size_t)z*L + l)*NC + c] = (_Float16)s;
  }
  // ---- p3 Bhat + rn3 ----
  {
    float K[9]; float ss = 0.f;
    #pragma unroll
    for(int i=0;i<3;i++)
      #pragma unroll
      for(int j=0;j<3;j++){
        const float v = Wn[1+i][1+j]*(1.0f - m3[i][j]) + 1e-7f;
        K[i*3+j] = v; ss += v*v;
      }
    ss = wave_sum(ss);
    const float rn = rsqrtf(ss);
    _Float16* outp = BhatH3 + ((size_t)z*L + l)*D3 + c*9;
    #pragma unroll
    for(int k=0;k<9;k++) outp[k] = (_Float16)(K[k]*rn);
    if(c==0) rn3[(size_t)z*L + l] = rn;
  }
  // ---- p3 PfgBox ----
  {
    const bool dyok[3] = { y-1>=0, true, y+1<HH };
    const bool dxok[3] = { x-1>=0, true, x+1<WW };
    _Float16* outp = PfgH3 + ((size_t)z*L + l)*D3 + c*9;
    #pragma unroll
    for(int i=0;i<3;i++)
      #pragma unroll
      for(int j=0;j<3;j++){
        float acc = 0.f;
        #pragma unroll
        for(int a=0;a<3;a++){
          if(!dyok[a]) continue;
          #pragma unroll
          for(int b=0;b<3;b++){
            if(!dxok[b]) continue;
            acc += Wn[i+a][j+b];
          }
        }
        outp[i*3+j] = (_Float16)acc;
      }
  }
}

__global__ __launch_bounds__(256) void transpose_h(const ushort* __restrict__ src,
                                                   ushort* __restrict__ dst,
                                                   int C, size_t sSz, size_t sDz){
  __shared__ ushort tile[64][65];
  const int z = blockIdx.z;
  src += z*sSz; dst += z*sDz;
  const int bc = blockIdx.x*64, br = blockIdx.y*64;
  const int tx = threadIdx.x & 15, ty = threadIdx.x >> 4;
  #pragma unroll
  for(int i=0;i<4;i++){
    const ushort4 v = *(const ushort4*)(src + (size_t)(br+ty+16*i)*C + bc + tx*4);
    tile[ty+16*i][tx*4+0] = v.x;
    tile[ty+16*i][tx*4+1] = v.y;
    tile[ty+16*i][tx*4+2] = v.z;
    tile[ty+16*i][tx*4+3] = v.w;
  }
  __syncthreads();
  #pragma unroll
  for(int i=0;i<4;i++){
    ushort4 o;
    o.x = tile[tx*4+0][ty+16*i];
    o.y = tile[tx*4+1][ty+16*i];
    o.z = tile[tx*4+2][ty+16*i];
    o.w = tile[tx*4+3][ty+16*i];
    *(ushort4*)(dst + (size_t)(bc+ty+16*i)*L + br + tx*4) = o;
  }
}

// ---------------- barrier-free per-wave flash attention (p=1) ----------------
__global__ __launch_bounds__(256) void flash_p1(const _Float16* __restrict__ Q,
                                                const _Float16* __restrict__ Km,
                                                const _Float16* __restrict__ Vt,
                                                float* __restrict__ Op,
                                                float* __restrict__ Ml,
                                                float* __restrict__ Ll){
  __shared__ _Float16 Qs[QB*64];
  __shared__ _Float16 KsA[4][QB*64];
  __shared__ _Float16 VsA[4][64*32];
  __shared__ _Float16 PsA[4][QB*32];
  __shared__ float    FwA[4][QB];
  const int z = blockIdx.z, sp = blockIdx.y, q0 = blockIdx.x*QB;
  const int t = threadIdx.x, lane = t&63, wave = t>>6;
  const int r16 = lane&15, g4 = lane>>4;
  _Float16* Ks = KsA[wave];
  _Float16* Vs = VsA[wave];
  _Float16* Ps = PsA[wave];
  float* Fw = FwA[wave];
  {
    const int row = t>>3, ch = t&7;
    gload16(Q + ((size_t)z*L + q0 + row)*64 + ((ch ^ (row&7))<<3), (char*)Qs + t*16);
  }
  asm volatile("s_waitcnt vmcnt(0)" ::: "memory");
  __syncthreads();

  float Mreg[2] = {-3.0e38f, -3.0e38f};
  float Lreg[2] = {0.f, 0.f};
  f32x4 accO[2][4] = {};

  for(int tt=0; tt<8; ++tt){
    const int lbase = sp*1024 + tt*128 + wave*32;
    #pragma unroll
    for(int u=0;u<4;u++){
      const int row = u*8 + (lane>>3), ch = lane&7;
      gload16(Km + ((size_t)z*L + lbase + row)*64 + ((ch ^ (row&7))<<3),
              (char*)Ks + u*1024 + lane*16);
    }
    #pragma unroll
    for(int u=0;u<4;u++){
      const int cst = u*16 + (lane>>2), slot = lane&3;
      gload16(Vt + ((size_t)z*64 + cst)*L + lbase + ((slot ^ (cst&3))<<3),
              (char*)Vs + u*1024 + lane*16);
    }
    asm volatile("s_waitcnt vmcnt(0)" ::: "memory");
    __builtin_amdgcn_sched_barrier(0);
    f32x4 acc[2][2] = {};
    #pragma unroll
    for(int kk=0;kk<2;kk++){
      f16x8 af[2], bf[2];
      #pragma unroll
      for(int i=0;i<2;i++){
        const int row = i*16 + r16;
        af[i] = *(const f16x8*)((const char*)Ks + (((row<<7) + kk*64 + (g4<<4)) ^ ((row&7)<<4)));
      }
      #pragma unroll
      for(int j=0;j<2;j++){
        const int row = j*16 + r16;
        bf[j] = *(const f16x8*)((const char*)Qs + (((row<<7) + kk*64 + (g4<<4)) ^ ((row&7)<<4)));
      }
      #pragma unroll
      for(int i=0;i<2;i++)
        #pragma unroll
        for(int j=0;j<2;j++)
          acc[i][j] = __builtin_amdgcn_mfma_f32_16x16x32_f16(af[i], bf[j], acc[i][j], 0,0,0);
    }
    float fs[2];
    #pragma unroll
    for(int j=0;j<2;j++){
      float mv = -3.0e38f;
      #pragma unroll
      for(int i=0;i<2;i++)
        #pragma unroll
        for(int r=0;r<4;r++) mv = fmaxf(mv, acc[i][j][r]);
      mv = fmaxf(mv, __shfl_xor(mv, 16));
      mv = fmaxf(mv, __shfl_xor(mv, 32));
      const float mnew = fmaxf(Mreg[j], mv);
      fs[j] = __expf(Mreg[j] - mnew);
      Mreg[j] = mnew;
      float ps = 0.f;
      const int q = j*16 + r16;
      #pragma unroll
      for(int i=0;i<2;i++){
        f16x4 ph;
        #pragma unroll
        for(int r=0;r<4;r++){
          const float p = __expf(acc[i][j][r] - mnew);
          ps += p; ph[r] = (_Float16)p;
        }
        *(f16x4*)((char*)Ps + (q<<6) + ((i*32 + g4*8) ^ ((q&3)<<4))) = ph;
      }
      ps += __shfl_xor(ps, 16);
      ps += __shfl_xor(ps, 32);
      Lreg[j] = Lreg[j]*fs[j] + ps;
    }
    if(g4==0){ Fw[r16] = fs[0]; Fw[16+r16] = fs[1]; }
    #pragma unroll
    for(int qb=0;qb<2;qb++){
      float f4[4];
      #pragma unroll
      for(int r=0;r<4;r++) f4[r] = Fw[qb*16 + g4*4 + r];
      #pragma unroll
      for(int cb=0;cb<4;cb++)
        #pragma unroll
        for(int r=0;r<4;r++) accO[qb][cb][r] *= f4[r];
    }
    #pragma unroll
    for(int qb=0;qb<2;qb++){
      const int qrow = qb*16 + r16;
      const f16x8 af = *(const f16x8*)((const char*)Ps + (qrow<<6) + ((g4<<4) ^ ((qrow&3)<<4)));
      #pragma unroll
      for(int cb=0;cb<4;cb++){
        const int crow = cb*16 + r16;
        const f16x8 bf = *(const f16x8*)((const char*)Vs + (crow<<6) + ((g4<<4) ^ ((crow&3)<<4)));
        accO[qb][cb] = __builtin_amdgcn_mfma_f32_16x16x32_f16(af, bf, accO[qb][cb], 0,0,0);
      }
    }
  }
  const int sidx = (z*NSPLIT + sp)*4 + wave;
  #pragma unroll
  for(int qb=0;qb<2;qb++){
    #pragma unroll
    for(int cb=0;cb<4;cb++){
      #pragma unroll
      for(int r=0;r<4;r++){
        const int ql = qb*16 + g4*4 + r;
        Op[((size_t)sidx*L + q0 + ql)*64 + cb*16 + r16] = accO[qb][cb][r];
      }
    }
  }
  if(g4==0){
    Ml[(size_t)sidx*L + q0 + r16]      = Mreg[0];
    Ml[(size_t)sidx*L + q0 + 16 + r16] = Mreg[1];
    Ll[(size_t)sidx*L + q0 + r16]      = Lreg[0];
    Ll[(size_t)sidx*L + q0 + 16 + r16] = Lreg[1];
  }
}

// OM=2: fp16 output (KS=1), 2D XCD-region swizzle; OM=3: fp16 split-K partials.
template<int OM, int KS>
__global__ __launch_bounds__(256, 3) void gemm_h16(const _Float16* __restrict__ A, int lda, size_t sAz,
                                                   const _Float16* __restrict__ B, int ldb, size_t sBz,
                                                   void* __restrict__ C, int ldc, size_t sCz,
                                                   int K, size_t sPart){
  __shared__ _Float16 sh[16384];   // As(8192) + Bs(8192) = 32768 B total
  _Float16* As = sh;
  _Float16* Bs = sh + 8192;
  const int zz = blockIdx.z;
  const int z = zz / KS, ks = zz % KS;
  const int Kp = K / KS;
  A += (size_t)z*sAz + (size_t)ks*Kp;
  B += (size_t)z*sBz + (size_t)ks*Kp;
  int bxi = blockIdx.x, byi = blockIdx.y;
  if(OM==2){
    const int i = byi*32 + bxi;
    const int xcd = i & 7, tt = (i >> 3) & 127;
    byi = 8*(xcd & 3) + (tt & 7);
    bxi = 16*(xcd >> 2) + (tt >> 3);
  }
  const int bm = byi*128, bn = bxi*128;
  const int t = threadIdx.x, lane = t & 63, wave = t >> 6;
  const int wr = wave >> 1, wc = wave & 1;
  const int r16 = lane & 15, g4 = lane >> 4;
  const int srow = t >> 3;
  const int schunk = t & 7;
  f32x4 acc[4][4] = {};
  for(int k0=0;k0<Kp;k0+=64){
    #pragma unroll
    for(int u=0;u<4;u++){
      const int rowA = u*32 + srow;
      const int colh = ((schunk ^ (rowA & 7)) << 3);
      gload16(A + (size_t)(bm+rowA)*lda + k0 + colh, (char*)As + u*4096 + wave*1024);
      gload16(B + (size_t)(bn+rowA)*ldb + k0 + colh, (char*)Bs + u*4096 + wave*1024);
    }
    __syncthreads();
    #pragma unroll
    for(int kk=0;kk<2;kk++){
      f16x8 af[4], bf[4];
      #pragma unroll
      for(int i=0;i<4;i++){
        const int row = wr*64 + i*16 + r16;
        const int off = ((row<<7) + kk*64 + (g4<<4)) ^ ((row&7)<<4);
        af[i] = *(const f16x8*)((const char*)As + off);
      }
      #pragma unroll
      for(int j=0;j<4;j++){
        const int row = wc*64 + j*16 + r16;
        const int off = ((row<<7) + kk*64 + (g4<<4)) ^ ((row&7)<<4);
        bf[j] = *(const f16x8*)((const char*)Bs + off);
      }
      #pragma unroll
      for(int i=0;i<4;i++)
        #pragma unroll
        for(int j=0;j<4;j++)
          acc[i][j] = __builtin_amdgcn_mfma_f32_16x16x32_f16(af[i], bf[j], acc[i][j], 0, 0, 0);
    }
    __syncthreads();
  }
  // two-half LDS-transpose fp16 epilogue (reuses As/Bs space)
  _Float16* Cz = (_Float16*)C + (OM==2 ? (size_t)z*sCz
                                       : (size_t)ks*sPart + (size_t)z*sCz);
  #pragma unroll
  for(int h=0; h<2; ++h){
    __syncthreads();
    if(wr == h){
      #pragma unroll
      for(int i=0;i<4;i++){
        const int row0 = i*16 + g4*4;
        #pragma unroll
        for(int j=0;j<4;j++){
          const int col = wc*64 + j*16 + r16;
          #pragma unroll
          for(int r=0;r<4;r++)
            sh[(row0+r)*136 + col] = (_Float16)acc[i][j][r];
        }
      }
    }
    __syncthreads();
    #pragma unroll
    for(int k=0;k<4;k++){
      const int row = k*16 + (t>>4);
      const int cg = (t&15)*8;
      const f16x8 v = *(const f16x8*)(sh + row*136 + cg);
      *(f16x8*)(Cz + (size_t)(bm + h*64 + row)*ldc + bn + cg) = v;
    }
  }
}

__global__ __launch_bounds__(256) void softmax_rn(_Float16* __restrict__ S,
                                                  const float* __restrict__ rn3,
                                                  float* __restrict__ Tq){
  __shared__ float red[4];
  const int q = blockIdx.x, z = blockIdx.y, t = threadIdx.x;
  _Float16* p = S + ((size_t)z*L + q)*L;
  float v[16];
  {
    const f16x8 a = *(const f16x8*)(p + t*16);
    const f16x8 b = *(const f16x8*)(p + t*16 + 8);
    #pragma unroll
    for(int i=0;i<8;i++){ v[i] = (float)a[i]; v[8+i] = (float)b[i]; }
  }
  float mx = -3.0e38f;
  #pragma unroll
  for(int i=0;i<16;i++) mx = fmaxf(mx, v[i]);
  mx = wave_max(mx);
  if((t&63)==0) red[t>>6]=mx;
  __syncthreads();
  mx = fmaxf(fmaxf(red[0],red[1]), fmaxf(red[2],red[3]));
  __syncthreads();
  float s = 0.f;
  #pragma unroll
  for(int i=0;i<16;i++){ v[i] = __expf(v[i]-mx); s += v[i]; }
  s = wave_sum(s);
  if((t&63)==0) red[t>>6]=s;
  __syncthreads();
  s = red[0]+red[1]+red[2]+red[3];
  __syncthreads();
  const float inv = 1.0f/s;
  const float* rnz = rn3 + (size_t)z*L + t*16;
  float T = 0.f;
  f16x8 a, b;
  #pragma unroll
  for(int i=0;i<8;i++){
    const float w0 = v[i]*inv*rnz[i];
    const float w1 = v[8+i]*inv*rnz[8+i];
    T += w0 + w1;
    a[i] = (_Float16)(w0*ASCALE);
    b[i] = (_Float16)(w1*ASCALE);
  }
  *(f16x8*)(p + t*16) = a;
  *(f16x8*)(p + t*16 + 8) = b;
  T = wave_sum(T);
  if((t&63)==0) red[t>>6]=T;
  __syncthreads();
  if(t==0) Tq[(size_t)z*L + q] = red[0]+red[1]+red[2]+red[3];
}

// ---------------- 9-tap diagonal stencil, half-width staged ----------------
__global__ __launch_bounds__(256) void d9_pass(const _Float16* __restrict__ in,
                                               _Float16* __restrict__ out){
  __shared__ _Float16 rows[9*D9W];
  const int bx = blockIdx.x, by = blockIdx.y, t = threadIdx.x;
  const int a = (bx&7)*512 + (bx>>3);
  const int z = by & 1, h = by >> 1;
  const int cbase = h*2048 - 72;
  const int ya = a>>6, xa = a&63;
  const int DY[9] = {-1,-1,-1, 0,0,0, 1,1,1};
  const int DX[9] = {-1, 0, 1,-1,0,1,-1,0,1};
  bool vr[9];
  #pragma unroll
  for(int k=0;k<9;k++){
    const int yy = ya + DY[k], xx = xa + DX[k];
    vr[k] = (yy>=0 && yy<64 && xx>=0 && xx<64);
    if(vr[k]){
      const _Float16* src = in + ((size_t)z*L + a + DY[k]*64 + DX[k])*L;
      int g0 = cbase + t*8;
      g0 = g0 < 0 ? 0 : g0;
      gload16(src + g0, (char*)rows + k*(D9W*2) + t*16);
      const int g1 = cbase + (256+t)*8;
      if(t < 18 && g1 < L)
        gload16(src + g1, (char*)rows + k*(D9W*2) + 4096 + t*16);
    }
  }
  __syncthreads();
  const int m0 = h*2048 + t*8;
  const int ym = m0>>6, x0 = m0&63;
  float o[8] = {0,0,0,0,0,0,0,0};
  #pragma unroll
  for(int k=0;k<9;k++){
    const int D = DY[k]*64 + DX[k];
    const bool vy = vr[k] && ((unsigned)(ym + DY[k]) < 64u);
    if(!vy) continue;
    const int r = ((D % 8) + 8) % 8;
    const int loff = t*8 + 72 + D - r;
    const _Float16* p = rows + k*D9W + loff;
    _Float16 buf[16];
    *(f16x8*)(buf)   = *(const f16x8*)(p);
    *(f16x8*)(buf+8) = *(const f16x8*)(p+8);
    #pragma unroll
    for(int i=0;i<8;i++){
      const bool vx = (unsigned)(x0 + i + DX[k]) < 64u;
      o[i] += vx ? (float)buf[r + i] : 0.f;
    }
  }
  f16x8 w0;
  #pragma unroll
  for(int i=0;i<8;i++) w0[i] = (_Float16)o[i];
  *(f16x8*)(out + ((size_t)z*L + a)*L + m0) = w0;
}

// ---------------- fused epilogue: flash combine + p3 scatter + SE partials ----------
__global__ __launch_bounds__(256) void epilogue_qc(const float* __restrict__ Op,
                                                   const float* __restrict__ Ml,
                                                   const float* __restrict__ Ll,
                                                   const _Float16* __restrict__ Cp,
                                                   const float* __restrict__ Tq,
                                                   const float* __restrict__ fgT,
                                                   const float* __restrict__ mask,
                                                   float* __restrict__ outs,
                                                   float* __restrict__ part,
                                                   size_t sPart){
  __shared__ float ps[4][128];
  const int z = blockIdx.y, t = threadIdx.x;
  const int sub = t >> 6;
  const int q = blockIdx.x*4 + sub, c = t & 63;
  const float m = mask[(size_t)z*L + q];
  const float f = fgT[((size_t)z*L + q)*64 + c];
  float o1, o3;
  // ---- p1: combine 16 raw fp32 flash partial sets ----
  {
    float mv[16];
    float ms = -3.0e38f;
    #pragma unroll
    for(int s=0;s<16;s++){
      mv[s] = Ml[(size_t)(z*16+s)*L + q];
      ms = fmaxf(ms, mv[s]);
    }
    float acc = 0.f, Lt = 0.f;
    #pragma unroll
    for(int s=0;s<16;s++){
      const float w0 = __expf(mv[s] - ms);
      acc += w0 * Op[((size_t)(z*16+s)*L + q)*64 + c];
      Lt  += w0 * Ll[(size_t)(z*16+s)*L + q];
    }
    const float o = acc/Lt;
    o1 = o*m + f*(1.0f-m);
    outs[((size_t)z*L + q)*128 + c] = o1;
  }
  // ---- p3: split-K reduce + eps + mask mix ----
  {
    const int y = q >> 6, x = q & 63;
    const size_t idx = ((size_t)z*L + q)*128 + c;
    float rec = 0.f;
    #pragma unroll
    for(int k=0;k<8;k++) rec += (float)Cp[(size_t)k*sPart + idx];
    float tb = 0.f;
    #pragma unroll
    for(int dy=-1;dy<=1;dy++){
      const int yy = y+dy;
      if(yy<0||yy>=64) continue;
      #pragma unroll
      for(int dx=-1;dx<=1;dx++){
        const int xx = x+dx;
        if(xx<0||xx>=64) continue;
        tb += Tq[(size_t)z*L + yy*64+xx];
      }
    }
    rec += 1e-7f*tb;
    o3 = rec*(m*(1.0f/9.0f)) + f*(1.0f-m);
    outs[((size_t)z*L + q)*128 + 64 + c] = o3;
  }
  // ---- SE channel partials ----
  ps[sub][c] = o1;
  ps[sub][64 + c] = o3;
  __syncthreads();
  if(t < 128){
    const float s = ps[0][t] + ps[1][t] + ps[2][t] + ps[3][t];
    part[((size_t)z*1024 + blockIdx.x)*128 + t] = s;
  }
}

// ---------------- SE MLP (512 threads) ----------------
__global__ __launch_bounds__(512) void se_mlp(const float* __restrict__ part,
                                              const float* __restrict__ W1, const float* __restrict__ b1,
                                              const float* __restrict__ W2, const float* __restrict__ b2,
                                              float* __restrict__ g){
  __shared__ float red[4][128];
  __shared__ float s[128], h[128];
  const int z = blockIdx.x, t = threadIdx.x;
  const int ch = t & 127, sl = t >> 7;
  float a0 = 0.f;
  for(int j=sl*256; j<(sl+1)*256; ++j)
    a0 += part[((size_t)z*1024 + j)*128 + ch];
  red[sl][ch] = a0;
  __syncthreads();
  if(t < 128) s[t] = (red[0][t]+red[1][t]+red[2][t]+red[3][t])*(1.0f/4096.0f);
  __syncthreads();
  if(t < 128){
    float a = b1[t];
    const float* w = W1 + (size_t)t*128;
    for(int j=0;j<128;j++) a = fmaf(w[j], s[j], a);
    h[t] = fmaxf(a, 0.f);
  }
  __syncthreads();
  if(t < 128){
    float o = b2[t];
    const float* w = W2 + (size_t)t*128;
    for(int j=0;j<128;j++) o = fmaf(w[j], h[j], o);
    g[z*128+t] = 1.0f/(1.0f + __expf(-o));
  }
}

// ---------------- combiner: LDS-tiled 1x1 conv — outs read ONCE ----------------
// Block: 32 queries x all 64 outputs. Stage g-scaled outs transposed in LDS.
__global__ __launch_bounds__(256) void combiner(const float* __restrict__ outs,
                                                const float* __restrict__ g,
                                                const float* __restrict__ Wc,
                                                const float* __restrict__ bc,
                                                float* __restrict__ out){
  __shared__ float sc[128][33];          // [ch][qi], +1 pad -> conflict-free reads
  const int z = blockIdx.y, q0 = blockIdx.x*32, t = threadIdx.x;
  const float* gz = g + z*128;
  // stage: 4 iters x 8 q rows (256 threads x float4 = 1024 floats/iter), coalesced
  #pragma unroll
  for(int it=0; it<4; ++it){
    const int qi = it*8 + (t>>5);
    const int c4 = (t&31)*4;
    const float4 v = *(const float4*)(outs + ((size_t)z*L + q0 + qi)*128 + c4);
    sc[c4+0][qi] = v.x*gz[c4+0];
    sc[c4+1][qi] = v.y*gz[c4+1];
    sc[c4+2][qi] = v.z*gz[c4+2];
    sc[c4+3][qi] = v.w*gz[c4+3];
  }
  __syncthreads();
  const int qi = t & 31, ob = t >> 5;    // ob in 0..7 -> o = ob*8 + k, k<8
  float acc[8];
  #pragma unroll
  for(int k=0;k<8;k++) acc[k] = bc[ob*8+k];
  for(int ch=0; ch<128; ++ch){
    const float v = sc[ch][qi];
    #pragma unroll
    for(int k=0;k<8;k++)
      acc[k] = fmaf(v, Wc[(size_t)(ob*8+k)*128 + ch], acc[k]);
  }
  #pragma unroll
  for(int k=0;k<8;k++){
    const int o = ob*8 + k;
    out[((size_t)z*64 + o)*L + q0 + qi] = acc[k];
  }
}

extern "C" void kernel_launch(void* const* d_in, const int* in_sizes, int n_in,
                              void* d_out, int out_size, void* d_ws, size_t ws_size,
                              hipStream_t stream){
  const float* fg   = (const float*)d_in[0];
  const float* mask = (const float*)d_in[1];
  const float* W1   = (const float*)d_in[2];
  const float* b1   = (const float*)d_in[3];
  const float* W2   = (const float*)d_in[4];
  const float* b2   = (const float*)d_in[5];
  const float* Wc   = (const float*)d_in[6];
  const float* bc   = (const float*)d_in[7];
  float* out = (float*)d_out;

  char* w = (char*)d_ws;
  size_t off = 0;
  auto alloc = [&](size_t bytes)->void*{
    void* p = (void*)(w + off);
    off += (bytes + 255) & ~(size_t)255;
    return p;
  };
  _Float16* S    = (_Float16*)alloc(2ull*L*L*2);   // p3 scores / A''
  _Float16* DxB  = (_Float16*)alloc(2ull*L*L*2);   // d9 output G
  _Float16* Cp16 = (_Float16*)alloc(8ull*2*L*128*2); // fp16 split-K partials
  float* outs  = (float*)alloc(2ull*L*128*4);
  float* fgT   = (float*)alloc(2ull*L*64*4);
  _Float16* BhatH1 = (_Float16*)alloc(2ull*L*64*2);
  _Float16* BhatT1 = (_Float16*)alloc(2ull*64*L*2);
  _Float16* PfgH1  = (_Float16*)alloc(2ull*L*64*2);
  _Float16* BhatH3 = (_Float16*)alloc(2ull*L*D3*2);
  _Float16* PfgH3  = (_Float16*)alloc(2ull*L*D3*2);
  _Float16* bgH    = (_Float16*)alloc(2ull*128*L*2);
  float* Opb  = (float*)alloc((size_t)32*L*64*4);   // raw fp32 flash partials
  float* Mlb  = (float*)alloc((size_t)32*L*4);
  float* Llb  = (float*)alloc((size_t)32*L*4);
  float* rn3v = (float*)alloc(2ull*L*4);
  float* Tq   = (float*)alloc(2ull*L*4);
  float* part = (float*)alloc(2ull*1024*128*4);
  float* gbuf = (float*)alloc(1024);
  const size_t sPart = 2ull*L*128;   // elements per split (fp16)

  // ================= prep (fused transpose + bgH) =================
  prep_fg<<<dim3(64,2),256,0,stream>>>(fg, mask, fgT, bgH);
  build_all<<<dim3(L/4,2),256,0,stream>>>(fgT, mask, BhatH1, PfgH1, BhatH3, PfgH3, rn3v);
  transpose_h<<<dim3(1,64,2),256,0,stream>>>((const ushort*)BhatH1, (ushort*)BhatT1,
                                             64, (size_t)L*64, (size_t)64*L);

  // ================= p=1 branch (barrier-free flash, 16-way split) =================
  flash_p1<<<dim3(L/QB,NSPLIT,2),256,0,stream>>>(PfgH1, BhatH1, BhatT1, Opb, Mlb, Llb);

  // ================= p=3 branch =================
  gemm_h16<2,1><<<dim3(32,32,2),256,0,stream>>>(
      PfgH3, D3, (size_t)L*D3,
      BhatH3, D3, (size_t)L*D3,
      (void*)S, L, (size_t)L*L, D3, 0);
  softmax_rn<<<dim3(L,2),256,0,stream>>>(S, rn3v, Tq);
  d9_pass<<<dim3(L,4),256,0,stream>>>(S, DxB);
  gemm_h16<3,8><<<dim3(1,32,16),256,0,stream>>>(
      DxB, L, (size_t)L*L,
      bgH, L, (size_t)128*L,
      (void*)Cp16, 128, (size_t)L*128, L, sPart);

  // ================= fused epilogue (both branches + SE partials) =================
  epilogue_qc<<<dim3(L/4,2),256,0,stream>>>(Opb, Mlb, Llb, Cp16, Tq, fgT, mask,
                                            outs, part, sPart);

  // ================= SE + combiner =================
  se_mlp<<<2,512,0,stream>>>(part, W1, b1, W2, b2, gbuf);
  combiner<<<dim3(L/32,2),256,0,stream>>>(outs, gbuf, Wc, bc, out);
}

// Round 20
// 221.361 us; speedup vs baseline: 1.1714x; 1.0125x over previous
//
#include <hip/hip_runtime.h>
#include <math.h>

#define WW 64
#define HH 64
#define L 4096
#define NC 64
#define D3 576
#define ASCALE (1.0f/128.0f)
#define QB 32
#define NSPLIT 4          // key-slices per z; 4 waves each -> 16 partial sets per z
#define D9W 2200          // staged cols per row-half (2192 used + pad)

typedef _Float16 f16x8 __attribute__((ext_vector_type(8)));
typedef _Float16 f16x4 __attribute__((ext_vector_type(4)));
typedef float    f32x4 __attribute__((ext_vector_type(4)));

__device__ __forceinline__ float wave_max(float v){
  #pragma unroll
  for(int o=32;o;o>>=1) v = fmaxf(v, __shfl_xor(v,o));
  return v;
}
__device__ __forceinline__ float wave_sum(float v){
  #pragma unroll
  for(int o=32;o;o>>=1) v += __shfl_xor(v,o);
  return v;
}
__device__ __forceinline__ void gload16(const void* g, void* l){
  __builtin_amdgcn_global_load_lds((const __attribute__((address_space(1))) unsigned int*)g,
                                   (__attribute__((address_space(3))) unsigned int*)l,
                                   16, 0, 0);
}

// ---------------- fused: fg transpose + bgH build ----------------
__global__ __launch_bounds__(256) void prep_fg(const float* __restrict__ fg,
                                               const float* __restrict__ mask,
                                               float* __restrict__ fgT,
                                               _Float16* __restrict__ bgH){
  __shared__ float tile[64][65];
  __shared__ float msh[64];
  const int z = blockIdx.y;
  const int q0 = blockIdx.x*64;
  const int tx = threadIdx.x & 63, ty = threadIdx.x >> 6;
  if(threadIdx.x < 64) msh[threadIdx.x] = mask[(size_t)z*L + q0 + threadIdx.x];
  #pragma unroll
  for(int i=0;i<16;i++){
    const int c = ty*16 + i;
    tile[c][tx] = fg[((size_t)z*64 + c)*L + q0 + tx];
  }
  __syncthreads();
  #pragma unroll
  for(int i=0;i<16;i++){
    const int q = ty*16 + i;
    fgT[((size_t)z*L + q0 + q)*64 + tx] = tile[tx][q];
  }
  const float mval = (1.0f - msh[tx])*128.0f;
  #pragma unroll
  for(int i=0;i<16;i++){
    const int c = ty*16 + i;
    bgH[((size_t)z*128 + c)*L + q0 + tx] = (_Float16)(tile[c][tx]*mval);
    bgH[((size_t)z*128 + 64 + c)*L + q0 + tx] = (_Float16)0.f;
  }
}

// ---------------- fused builder: p1 (Bhat,Pfg) + p3 (Bhat,rn3,PfgBox) ----------------
__global__ __launch_bounds__(256) void build_all(const float* __restrict__ fgT,
                                                 const float* __restrict__ mask,
                                                 _Float16* __restrict__ BhatH1,
                                                 _Float16* __restrict__ PfgH1,
                                                 _Float16* __restrict__ BhatH3,
                                                 _Float16* __restrict__ PfgH3,
                                                 float* __restrict__ rn3){
  const int t = threadIdx.x, c = t & 63, sub = t >> 6;
  const int l = blockIdx.x*4 + sub, z = blockIdx.y;
  const float* fgz = fgT + (size_t)z*L*64;
  const float* mz  = mask + (size_t)z*L;
  const int y = l >> 6, x = l & 63;
  float Wn[5][5];
  #pragma unroll
  for(int u=0;u<5;u++){
    const int yy = y+u-2;
    #pragma unroll
    for(int v=0;v<5;v++){
      const int xx = x+v-2;
      Wn[u][v] = (yy>=0 && yy<HH && xx>=0 && xx<WW) ? fgz[(size_t)(yy*WW+xx)*64 + c] : 0.f;
    }
  }
  float m3[3][3];
  #pragma unroll
  for(int i=0;i<3;i++){
    #pragma unroll
    for(int j=0;j<3;j++){
      const int yy = y+i-1, xx = x+j-1;
      m3[i][j] = (yy>=0&&yy<HH&&xx>=0&&xx<WW) ? mz[yy*WW+xx] : 0.f;
    }
  }
  // ---- p1 ----
  {
    const float K1 = Wn[2][2]*(1.0f - m3[1][1]) + 1e-7f;
    const float ss = wave_sum(K1*K1);
    BhatH1[((size_t)z*L + l)*NC + c] = (_Float16)(K1*rsqrtf(ss));
    float s = 0.f;
    #pragma unroll
    for(int a=0;a<3;a++)
      #pragma unroll
      for(int b=0;b<3;b++) s += Wn[1+a][1+b];
    PfgH1[((size_t)z*L + l)*NC + c] = (_Float16)s;
  }
  // ---- p3 Bhat + rn3 ----
  {
    float K[9]; float ss = 0.f;
    #pragma unroll
    for(int i=0;i<3;i++)
      #pragma unroll
      for(int j=0;j<3;j++){
        const float v = Wn[1+i][1+j]*(1.0f - m3[i][j]) + 1e-7f;
        K[i*3+j] = v; ss += v*v;
      }
    ss = wave_sum(ss);
    const float rn = rsqrtf(ss);
    _Float16* outp = BhatH3 + ((size_t)z*L + l)*D3 + c*9;
    #pragma unroll
    for(int k=0;k<9;k++) outp[k] = (_Float16)(K[k]*rn);
    if(c==0) rn3[(size_t)z*L + l] = rn;
  }
  // ---- p3 PfgBox ----
  {
    const bool dyok[3] = { y-1>=0, true, y+1<HH };
    const bool dxok[3] = { x-1>=0, true, x+1<WW };
    _Float16* outp = PfgH3 + ((size_t)z*L + l)*D3 + c*9;
    #pragma unroll
    for(int i=0;i<3;i++)
      #pragma unroll
      for(int j=0;j<3;j++){
        float acc = 0.f;
        #pragma unroll
        for(int a=0;a<3;a++){
          if(!dyok[a]) continue;
          #pragma unroll
          for(int b=0;b<3;b++){
            if(!dxok[b]) continue;
            acc += Wn[i+a][j+b];
          }
        }
        outp[i*3+j] = (_Float16)acc;
      }
  }
}

__global__ __launch_bounds__(256) void transpose_h(const ushort* __restrict__ src,
                                                   ushort* __restrict__ dst,
                                                   int C, size_t sSz, size_t sDz){
  __shared__ ushort tile[64][65];
  const int z = blockIdx.z;
  src += z*sSz; dst += z*sDz;
  const int bc = blockIdx.x*64, br = blockIdx.y*64;
  const int tx = threadIdx.x & 15, ty = threadIdx.x >> 4;
  #pragma unroll
  for(int i=0;i<4;i++){
    const ushort4 v = *(const ushort4*)(src + (size_t)(br+ty+16*i)*C + bc + tx*4);
    tile[ty+16*i][tx*4+0] = v.x;
    tile[ty+16*i][tx*4+1] = v.y;
    tile[ty+16*i][tx*4+2] = v.z;
    tile[ty+16*i][tx*4+3] = v.w;
  }
  __syncthreads();
  #pragma unroll
  for(int i=0;i<4;i++){
    ushort4 o;
    o.x = tile[tx*4+0][ty+16*i];
    o.y = tile[tx*4+1][ty+16*i];
    o.z = tile[tx*4+2][ty+16*i];
    o.w = tile[tx*4+3][ty+16*i];
    *(ushort4*)(dst + (size_t)(bc+ty+16*i)*L + br + tx*4) = o;
  }
}

// ---------------- barrier-free per-wave flash attention (p=1) ----------------
// Partials stored RAW in fp16 (|O| <= Lsum*max|V| <= 256; fp16 rel err 5e-4).
__global__ __launch_bounds__(256) void flash_p1(const _Float16* __restrict__ Q,
                                                const _Float16* __restrict__ Km,
                                                const _Float16* __restrict__ Vt,
                                                _Float16* __restrict__ Op,
                                                float* __restrict__ Ml,
                                                float* __restrict__ Ll){
  __shared__ _Float16 Qs[QB*64];
  __shared__ _Float16 KsA[4][QB*64];
  __shared__ _Float16 VsA[4][64*32];
  __shared__ _Float16 PsA[4][QB*32];
  __shared__ float    FwA[4][QB];
  const int z = blockIdx.z, sp = blockIdx.y, q0 = blockIdx.x*QB;
  const int t = threadIdx.x, lane = t&63, wave = t>>6;
  const int r16 = lane&15, g4 = lane>>4;
  _Float16* Ks = KsA[wave];
  _Float16* Vs = VsA[wave];
  _Float16* Ps = PsA[wave];
  float* Fw = FwA[wave];
  {
    const int row = t>>3, ch = t&7;
    gload16(Q + ((size_t)z*L + q0 + row)*64 + ((ch ^ (row&7))<<3), (char*)Qs + t*16);
  }
  asm volatile("s_waitcnt vmcnt(0)" ::: "memory");
  __syncthreads();

  float Mreg[2] = {-3.0e38f, -3.0e38f};
  float Lreg[2] = {0.f, 0.f};
  f32x4 accO[2][4] = {};

  for(int tt=0; tt<8; ++tt){
    const int lbase = sp*1024 + tt*128 + wave*32;
    #pragma unroll
    for(int u=0;u<4;u++){
      const int row = u*8 + (lane>>3), ch = lane&7;
      gload16(Km + ((size_t)z*L + lbase + row)*64 + ((ch ^ (row&7))<<3),
              (char*)Ks + u*1024 + lane*16);
    }
    #pragma unroll
    for(int u=0;u<4;u++){
      const int cst = u*16 + (lane>>2), slot = lane&3;
      gload16(Vt + ((size_t)z*64 + cst)*L + lbase + ((slot ^ (cst&3))<<3),
              (char*)Vs + u*1024 + lane*16);
    }
    asm volatile("s_waitcnt vmcnt(0)" ::: "memory");
    __builtin_amdgcn_sched_barrier(0);
    f32x4 acc[2][2] = {};
    #pragma unroll
    for(int kk=0;kk<2;kk++){
      f16x8 af[2], bf[2];
      #pragma unroll
      for(int i=0;i<2;i++){
        const int row = i*16 + r16;
        af[i] = *(const f16x8*)((const char*)Ks + (((row<<7) + kk*64 + (g4<<4)) ^ ((row&7)<<4)));
      }
      #pragma unroll
      for(int j=0;j<2;j++){
        const int row = j*16 + r16;
        bf[j] = *(const f16x8*)((const char*)Qs + (((row<<7) + kk*64 + (g4<<4)) ^ ((row&7)<<4)));
      }
      #pragma unroll
      for(int i=0;i<2;i++)
        #pragma unroll
        for(int j=0;j<2;j++)
          acc[i][j] = __builtin_amdgcn_mfma_f32_16x16x32_f16(af[i], bf[j], acc[i][j], 0,0,0);
    }
    float fs[2];
    #pragma unroll
    for(int j=0;j<2;j++){
      float mv = -3.0e38f;
      #pragma unroll
      for(int i=0;i<2;i++)
        #pragma unroll
        for(int r=0;r<4;r++) mv = fmaxf(mv, acc[i][j][r]);
      mv = fmaxf(mv, __shfl_xor(mv, 16));
      mv = fmaxf(mv, __shfl_xor(mv, 32));
      const float mnew = fmaxf(Mreg[j], mv);
      fs[j] = __expf(Mreg[j] - mnew);
      Mreg[j] = mnew;
      float ps = 0.f;
      const int q = j*16 + r16;
      #pragma unroll
      for(int i=0;i<2;i++){
        f16x4 ph;
        #pragma unroll
        for(int r=0;r<4;r++){
          const float p = __expf(acc[i][j][r] - mnew);
          ps += p; ph[r] = (_Float16)p;
        }
        *(f16x4*)((char*)Ps + (q<<6) + ((i*32 + g4*8) ^ ((q&3)<<4))) = ph;
      }
      ps += __shfl_xor(ps, 16);
      ps += __shfl_xor(ps, 32);
      Lreg[j] = Lreg[j]*fs[j] + ps;
    }
    if(g4==0){ Fw[r16] = fs[0]; Fw[16+r16] = fs[1]; }
    #pragma unroll
    for(int qb=0;qb<2;qb++){
      float f4[4];
      #pragma unroll
      for(int r=0;r<4;r++) f4[r] = Fw[qb*16 + g4*4 + r];
      #pragma unroll
      for(int cb=0;cb<4;cb++)
        #pragma unroll
        for(int r=0;r<4;r++) accO[qb][cb][r] *= f4[r];
    }
    #pragma unroll
    for(int qb=0;qb<2;qb++){
      const int qrow = qb*16 + r16;
      const f16x8 af = *(const f16x8*)((const char*)Ps + (qrow<<6) + ((g4<<4) ^ ((qrow&3)<<4)));
      #pragma unroll
      for(int cb=0;cb<4;cb++){
        const int crow = cb*16 + r16;
        const f16x8 bf = *(const f16x8*)((const char*)Vs + (crow<<6) + ((g4<<4) ^ ((crow&3)<<4)));
        accO[qb][cb] = __builtin_amdgcn_mfma_f32_16x16x32_f16(af, bf, accO[qb][cb], 0,0,0);
      }
    }
  }
  const int sidx = (z*NSPLIT + sp)*4 + wave;
  #pragma unroll
  for(int qb=0;qb<2;qb++){
    #pragma unroll
    for(int cb=0;cb<4;cb++){
      #pragma unroll
      for(int r=0;r<4;r++){
        const int ql = qb*16 + g4*4 + r;
        Op[((size_t)sidx*L + q0 + ql)*64 + cb*16 + r16] = (_Float16)accO[qb][cb][r];
      }
    }
  }
  if(g4==0){
    Ml[(size_t)sidx*L + q0 + r16]      = Mreg[0];
    Ml[(size_t)sidx*L + q0 + 16 + r16] = Mreg[1];
    Ll[(size_t)sidx*L + q0 + r16]      = Lreg[0];
    Ll[(size_t)sidx*L + q0 + 16 + r16] = Lreg[1];
  }
}

// OM=2: fp16 output (KS=1), 2D XCD-region swizzle; OM=3: fp16 split-K partials.
template<int OM, int KS>
__global__ __launch_bounds__(256, 3) void gemm_h16(const _Float16* __restrict__ A, int lda, size_t sAz,
                                                   const _Float16* __restrict__ B, int ldb, size_t sBz,
                                                   void* __restrict__ C, int ldc, size_t sCz,
                                                   int K, size_t sPart){
  __shared__ _Float16 sh[16384];   // As(8192) + Bs(8192) = 32768 B total
  _Float16* As = sh;
  _Float16* Bs = sh + 8192;
  const int zz = blockIdx.z;
  const int z = zz / KS, ks = zz % KS;
  const int Kp = K / KS;
  A += (size_t)z*sAz + (size_t)ks*Kp;
  B += (size_t)z*sBz + (size_t)ks*Kp;
  int bxi = blockIdx.x, byi = blockIdx.y;
  if(OM==2){
    const int i = byi*32 + bxi;
    const int xcd = i & 7, tt = (i >> 3) & 127;
    byi = 8*(xcd & 3) + (tt & 7);
    bxi = 16*(xcd >> 2) + (tt >> 3);
  }
  const int bm = byi*128, bn = bxi*128;
  const int t = threadIdx.x, lane = t & 63, wave = t >> 6;
  const int wr = wave >> 1, wc = wave & 1;
  const int r16 = lane & 15, g4 = lane >> 4;
  const int srow = t >> 3;
  const int schunk = t & 7;
  f32x4 acc[4][4] = {};
  for(int k0=0;k0<Kp;k0+=64){
    #pragma unroll
    for(int u=0;u<4;u++){
      const int rowA = u*32 + srow;
      const int colh = ((schunk ^ (rowA & 7)) << 3);
      gload16(A + (size_t)(bm+rowA)*lda + k0 + colh, (char*)As + u*4096 + wave*1024);
      gload16(B + (size_t)(bn+rowA)*ldb + k0 + colh, (char*)Bs + u*4096 + wave*1024);
    }
    __syncthreads();
    #pragma unroll
    for(int kk=0;kk<2;kk++){
      f16x8 af[4], bf[4];
      #pragma unroll
      for(int i=0;i<4;i++){
        const int row = wr*64 + i*16 + r16;
        const int off = ((row<<7) + kk*64 + (g4<<4)) ^ ((row&7)<<4);
        af[i] = *(const f16x8*)((const char*)As + off);
      }
      #pragma unroll
      for(int j=0;j<4;j++){
        const int row = wc*64 + j*16 + r16;
        const int off = ((row<<7) + kk*64 + (g4<<4)) ^ ((row&7)<<4);
        bf[j] = *(const f16x8*)((const char*)Bs + off);
      }
      #pragma unroll
      for(int i=0;i<4;i++)
        #pragma unroll
        for(int j=0;j<4;j++)
          acc[i][j] = __builtin_amdgcn_mfma_f32_16x16x32_f16(af[i], bf[j], acc[i][j], 0, 0, 0);
    }
    __syncthreads();
  }
  // two-half LDS-transpose fp16 epilogue (reuses As/Bs space)
  _Float16* Cz = (_Float16*)C + (OM==2 ? (size_t)z*sCz
                                       : (size_t)ks*sPart + (size_t)z*sCz);
  #pragma unroll
  for(int h=0; h<2; ++h){
    __syncthreads();
    if(wr == h){
      #pragma unroll
      for(int i=0;i<4;i++){
        const int row0 = i*16 + g4*4;
        #pragma unroll
        for(int j=0;j<4;j++){
          const int col = wc*64 + j*16 + r16;
          #pragma unroll
          for(int r=0;r<4;r++)
            sh[(row0+r)*136 + col] = (_Float16)acc[i][j][r];
        }
      }
    }
    __syncthreads();
    #pragma unroll
    for(int k=0;k<4;k++){
      const int row = k*16 + (t>>4);
      const int cg = (t&15)*8;
      const f16x8 v = *(const f16x8*)(sh + row*136 + cg);
      *(f16x8*)(Cz + (size_t)(bm + h*64 + row)*ldc + bn + cg) = v;
    }
  }
}

__global__ __launch_bounds__(256) void softmax_rn(_Float16* __restrict__ S,
                                                  const float* __restrict__ rn3,
                                                  float* __restrict__ Tq){
  __shared__ float red[4];
  const int q = blockIdx.x, z = blockIdx.y, t = threadIdx.x;
  _Float16* p = S + ((size_t)z*L + q)*L;
  float v[16];
  {
    const f16x8 a = *(const f16x8*)(p + t*16);
    const f16x8 b = *(const f16x8*)(p + t*16 + 8);
    #pragma unroll
    for(int i=0;i<8;i++){ v[i] = (float)a[i]; v[8+i] = (float)b[i]; }
  }
  float mx = -3.0e38f;
  #pragma unroll
  for(int i=0;i<16;i++) mx = fmaxf(mx, v[i]);
  mx = wave_max(mx);
  if((t&63)==0) red[t>>6]=mx;
  __syncthreads();
  mx = fmaxf(fmaxf(red[0],red[1]), fmaxf(red[2],red[3]));
  __syncthreads();
  float s = 0.f;
  #pragma unroll
  for(int i=0;i<16;i++){ v[i] = __expf(v[i]-mx); s += v[i]; }
  s = wave_sum(s);
  if((t&63)==0) red[t>>6]=s;
  __syncthreads();
  s = red[0]+red[1]+red[2]+red[3];
  __syncthreads();
  const float inv = 1.0f/s;
  const float* rnz = rn3 + (size_t)z*L + t*16;
  float T = 0.f;
  f16x8 a, b;
  #pragma unroll
  for(int i=0;i<8;i++){
    const float w0 = v[i]*inv*rnz[i];
    const float w1 = v[8+i]*inv*rnz[8+i];
    T += w0 + w1;
    a[i] = (_Float16)(w0*ASCALE);
    b[i] = (_Float16)(w1*ASCALE);
  }
  *(f16x8*)(p + t*16) = a;
  *(f16x8*)(p + t*16 + 8) = b;
  T = wave_sum(T);
  if((t&63)==0) red[t>>6]=T;
  __syncthreads();
  if(t==0) Tq[(size_t)z*L + q] = red[0]+red[1]+red[2]+red[3];
}

// ---------------- 9-tap diagonal stencil, half-width staged ----------------
__global__ __launch_bounds__(256) void d9_pass(const _Float16* __restrict__ in,
                                               _Float16* __restrict__ out){
  __shared__ _Float16 rows[9*D9W];
  const int bx = blockIdx.x, by = blockIdx.y, t = threadIdx.x;
  const int a = (bx&7)*512 + (bx>>3);
  const int z = by & 1, h = by >> 1;
  const int cbase = h*2048 - 72;
  const int ya = a>>6, xa = a&63;
  const int DY[9] = {-1,-1,-1, 0,0,0, 1,1,1};
  const int DX[9] = {-1, 0, 1,-1,0,1,-1,0,1};
  bool vr[9];
  #pragma unroll
  for(int k=0;k<9;k++){
    const int yy = ya + DY[k], xx = xa + DX[k];
    vr[k] = (yy>=0 && yy<64 && xx>=0 && xx<64);
    if(vr[k]){
      const _Float16* src = in + ((size_t)z*L + a + DY[k]*64 + DX[k])*L;
      int g0 = cbase + t*8;
      g0 = g0 < 0 ? 0 : g0;
      gload16(src + g0, (char*)rows + k*(D9W*2) + t*16);
      const int g1 = cbase + (256+t)*8;
      if(t < 18 && g1 < L)
        gload16(src + g1, (char*)rows + k*(D9W*2) + 4096 + t*16);
    }
  }
  __syncthreads();
  const int m0 = h*2048 + t*8;
  const int ym = m0>>6, x0 = m0&63;
  float o[8] = {0,0,0,0,0,0,0,0};
  #pragma unroll
  for(int k=0;k<9;k++){
    const int D = DY[k]*64 + DX[k];
    const bool vy = vr[k] && ((unsigned)(ym + DY[k]) < 64u);
    if(!vy) continue;
    const int r = ((D % 8) + 8) % 8;
    const int loff = t*8 + 72 + D - r;
    const _Float16* p = rows + k*D9W + loff;
    _Float16 buf[16];
    *(f16x8*)(buf)   = *(const f16x8*)(p);
    *(f16x8*)(buf+8) = *(const f16x8*)(p+8);
    #pragma unroll
    for(int i=0;i<8;i++){
      const bool vx = (unsigned)(x0 + i + DX[k]) < 64u;
      o[i] += vx ? (float)buf[r + i] : 0.f;
    }
  }
  f16x8 w0;
  #pragma unroll
  for(int i=0;i<8;i++) w0[i] = (_Float16)o[i];
  *(f16x8*)(out + ((size_t)z*L + a)*L + m0) = w0;
}

// ---------------- fused epilogue: flash combine + p3 scatter + SE partials ----------
__global__ __launch_bounds__(256) void epilogue_qc(const _Float16* __restrict__ Op,
                                                   const float* __restrict__ Ml,
                                                   const float* __restrict__ Ll,
                                                   const _Float16* __restrict__ Cp,
                                                   const float* __restrict__ Tq,
                                                   const float* __restrict__ fgT,
                                                   const float* __restrict__ mask,
                                                   float* __restrict__ outs,
                                                   float* __restrict__ part,
                                                   size_t sPart){
  __shared__ float ps[4][128];
  const int z = blockIdx.y, t = threadIdx.x;
  const int sub = t >> 6;
  const int q = blockIdx.x*4 + sub, c = t & 63;
  const float m = mask[(size_t)z*L + q];
  const float f = fgT[((size_t)z*L + q)*64 + c];
  float o1, o3;
  // ---- p1: combine 16 raw fp16 flash partial sets ----
  {
    float mv[16];
    float ms = -3.0e38f;
    #pragma unroll
    for(int s=0;s<16;s++){
      mv[s] = Ml[(size_t)(z*16+s)*L + q];
      ms = fmaxf(ms, mv[s]);
    }
    float acc = 0.f, Lt = 0.f;
    #pragma unroll
    for(int s=0;s<16;s++){
      const float w0 = __expf(mv[s] - ms);
      acc += w0 * (float)Op[((size_t)(z*16+s)*L + q)*64 + c];
      Lt  += w0 * Ll[(size_t)(z*16+s)*L + q];
    }
    const float o = acc/Lt;
    o1 = o*m + f*(1.0f-m);
    outs[((size_t)z*L + q)*128 + c] = o1;
  }
  // ---- p3: split-K reduce + eps + mask mix ----
  {
    const int y = q >> 6, x = q & 63;
    const size_t idx = ((size_t)z*L + q)*128 + c;
    float rec = 0.f;
    #pragma unroll
    for(int k=0;k<8;k++) rec += (float)Cp[(size_t)k*sPart + idx];
    float tb = 0.f;
    #pragma unroll
    for(int dy=-1;dy<=1;dy++){
      const int yy = y+dy;
      if(yy<0||yy>=64) continue;
      #pragma unroll
      for(int dx=-1;dx<=1;dx++){
        const int xx = x+dx;
        if(xx<0||xx>=64) continue;
        tb += Tq[(size_t)z*L + yy*64+xx];
      }
    }
    rec += 1e-7f*tb;
    o3 = rec*(m*(1.0f/9.0f)) + f*(1.0f-m);
    outs[((size_t)z*L + q)*128 + 64 + c] = o3;
  }
  // ---- SE channel partials ----
  ps[sub][c] = o1;
  ps[sub][64 + c] = o3;
  __syncthreads();
  if(t < 128){
    const float s = ps[0][t] + ps[1][t] + ps[2][t] + ps[3][t];
    part[((size_t)z*1024 + blockIdx.x)*128 + t] = s;
  }
}

// ---------------- SE MLP (512 threads) ----------------
__global__ __launch_bounds__(512) void se_mlp(const float* __restrict__ part,
                                              const float* __restrict__ W1, const float* __restrict__ b1,
                                              const float* __restrict__ W2, const float* __restrict__ b2,
                                              float* __restrict__ g){
  __shared__ float red[4][128];
  __shared__ float s[128], h[128];
  const int z = blockIdx.x, t = threadIdx.x;
  const int ch = t & 127, sl = t >> 7;
  float a0 = 0.f;
  for(int j=sl*256; j<(sl+1)*256; ++j)
    a0 += part[((size_t)z*1024 + j)*128 + ch];
  red[sl][ch] = a0;
  __syncthreads();
  if(t < 128) s[t] = (red[0][t]+red[1][t]+red[2][t]+red[3][t])*(1.0f/4096.0f);
  __syncthreads();
  if(t < 128){
    float a = b1[t];
    const float* w = W1 + (size_t)t*128;
    for(int j=0;j<128;j++) a = fmaf(w[j], s[j], a);
    h[t] = fmaxf(a, 0.f);
  }
  __syncthreads();
  if(t < 128){
    float o = b2[t];
    const float* w = W2 + (size_t)t*128;
    for(int j=0;j<128;j++) o = fmaf(w[j], h[j], o);
    g[z*128+t] = 1.0f/(1.0f + __expf(-o));
  }
}

// ---------------- combiner: LDS-tiled 1x1 conv — outs read ONCE ----------------
__global__ __launch_bounds__(256) void combiner(const float* __restrict__ outs,
                                                const float* __restrict__ g,
                                                const float* __restrict__ Wc,
                                                const float* __restrict__ bc,
                                                float* __restrict__ out){
  __shared__ float sc[128][33];          // [ch][qi], +1 pad -> conflict-free reads
  const int z = blockIdx.y, q0 = blockIdx.x*32, t = threadIdx.x;
  const float* gz = g + z*128;
  #pragma unroll
  for(int it=0; it<4; ++it){
    const int qi = it*8 + (t>>5);
    const int c4 = (t&31)*4;
    const float4 v = *(const float4*)(outs + ((size_t)z*L + q0 + qi)*128 + c4);
    sc[c4+0][qi] = v.x*gz[c4+0];
    sc[c4+1][qi] = v.y*gz[c4+1];
    sc[c4+2][qi] = v.z*gz[c4+2];
    sc[c4+3][qi] = v.w*gz[c4+3];
  }
  __syncthreads();
  const int qi = t & 31, ob = t >> 5;
  float acc[8];
  #pragma unroll
  for(int k=0;k<8;k++) acc[k] = bc[ob*8+k];
  for(int ch=0; ch<128; ++ch){
    const float v = sc[ch][qi];
    #pragma unroll
    for(int k=0;k<8;k++)
      acc[k] = fmaf(v, Wc[(size_t)(ob*8+k)*128 + ch], acc[k]);
  }
  #pragma unroll
  for(int k=0;k<8;k++){
    const int o = ob*8 + k;
    out[((size_t)z*64 + o)*L + q0 + qi] = acc[k];
  }
}

extern "C" void kernel_launch(void* const* d_in, const int* in_sizes, int n_in,
                              void* d_out, int out_size, void* d_ws, size_t ws_size,
                              hipStream_t stream){
  const float* fg   = (const float*)d_in[0];
  const float* mask = (const float*)d_in[1];
  const float* W1   = (const float*)d_in[2];
  const float* b1   = (const float*)d_in[3];
  const float* W2   = (const float*)d_in[4];
  const float* b2   = (const float*)d_in[5];
  const float* Wc   = (const float*)d_in[6];
  const float* bc   = (const float*)d_in[7];
  float* out = (float*)d_out;

  char* w = (char*)d_ws;
  size_t off = 0;
  auto alloc = [&](size_t bytes)->void*{
    void* p = (void*)(w + off);
    off += (bytes + 255) & ~(size_t)255;
    return p;
  };
  _Float16* S    = (_Float16*)alloc(2ull*L*L*2);   // p3 scores / A''
  _Float16* DxB  = (_Float16*)alloc(2ull*L*L*2);   // d9 output G
  _Float16* Cp16 = (_Float16*)alloc(8ull*2*L*128*2); // fp16 split-K partials
  float* outs  = (float*)alloc(2ull*L*128*4);
  float* fgT   = (float*)alloc(2ull*L*64*4);
  _Float16* BhatH1 = (_Float16*)alloc(2ull*L*64*2);
  _Float16* BhatT1 = (_Float16*)alloc(2ull*64*L*2);
  _Float16* PfgH1  = (_Float16*)alloc(2ull*L*64*2);
  _Float16* BhatH3 = (_Float16*)alloc(2ull*L*D3*2);
  _Float16* PfgH3  = (_Float16*)alloc(2ull*L*D3*2);
  _Float16* bgH    = (_Float16*)alloc(2ull*128*L*2);
  _Float16* Opb = (_Float16*)alloc((size_t)32*L*64*2);  // raw fp16 flash partials
  float* Mlb  = (float*)alloc((size_t)32*L*4);
  float* Llb  = (float*)alloc((size_t)32*L*4);
  float* rn3v = (float*)alloc(2ull*L*4);
  float* Tq   = (float*)alloc(2ull*L*4);
  float* part = (float*)alloc(2ull*1024*128*4);
  float* gbuf = (float*)alloc(1024);
  const size_t sPart = 2ull*L*128;   // elements per split (fp16)

  // ================= prep (fused transpose + bgH) =================
  prep_fg<<<dim3(64,2),256,0,stream>>>(fg, mask, fgT, bgH);
  build_all<<<dim3(L/4,2),256,0,stream>>>(fgT, mask, BhatH1, PfgH1, BhatH3, PfgH3, rn3v);
  transpose_h<<<dim3(1,64,2),256,0,stream>>>((const ushort*)BhatH1, (ushort*)BhatT1,
                                             64, (size_t)L*64, (size_t)64*L);

  // ================= p=1 branch (barrier-free flash, 16-way split) =================
  flash_p1<<<dim3(L/QB,NSPLIT,2),256,0,stream>>>(PfgH1, BhatH1, BhatT1, Opb, Mlb, Llb);

  // ================= p=3 branch =================
  gemm_h16<2,1><<<dim3(32,32,2),256,0,stream>>>(
      PfgH3, D3, (size_t)L*D3,
      BhatH3, D3, (size_t)L*D3,
      (void*)S, L, (size_t)L*L, D3, 0);
  softmax_rn<<<dim3(L,2),256,0,stream>>>(S, rn3v, Tq);
  d9_pass<<<dim3(L,4),256,0,stream>>>(S, DxB);
  gemm_h16<3,8><<<dim3(1,32,16),256,0,stream>>>(
      DxB, L, (size_t)L*L,
      bgH, L, (size_t)128*L,
      (void*)Cp16, 128, (size_t)L*128, L, sPart);

  // ================= fused epilogue (both branches + SE partials) =================
  epilogue_qc<<<dim3(L/4,2),256,0,stream>>>(Opb, Mlb, Llb, Cp16, Tq, fgT, mask,
                                            outs, part, sPart);

  // ================= SE + combiner =================
  se_mlp<<<2,512,0,stream>>>(part, W1, b1, W2, b2, gbuf);
  combiner<<<dim3(L/32,2),256,0,stream>>>(outs, gbuf, Wc, bc, out);
}

// Round 21
// 218.349 us; speedup vs baseline: 1.1876x; 1.0138x over previous
//
#include <hip/hip_runtime.h>
#include <math.h>

#define WW 64
#define HH 64
#define L 4096
#define NC 64
#define D3 576
#define ASCALE (1.0f/128.0f)
#define QB 32
#define NSPLIT 4          // key-slices per z; 4 waves each -> 16 partial sets per z
#define D9W 2200          // staged cols per row-half (2192 used + pad)

typedef _Float16 f16x8 __attribute__((ext_vector_type(8)));
typedef _Float16 f16x4 __attribute__((ext_vector_type(4)));
typedef float    f32x4 __attribute__((ext_vector_type(4)));

__device__ __forceinline__ float wave_max(float v){
  #pragma unroll
  for(int o=32;o;o>>=1) v = fmaxf(v, __shfl_xor(v,o));
  return v;
}
__device__ __forceinline__ float wave_sum(float v){
  #pragma unroll
  for(int o=32;o;o>>=1) v += __shfl_xor(v,o);
  return v;
}
__device__ __forceinline__ void gload16(const void* g, void* l){
  __builtin_amdgcn_global_load_lds((const __attribute__((address_space(1))) unsigned int*)g,
                                   (__attribute__((address_space(3))) unsigned int*)l,
                                   16, 0, 0);
}

// ---------------- fused: fg transpose + bgH build (bgH now [z][64][L]) ----------------
__global__ __launch_bounds__(256) void prep_fg(const float* __restrict__ fg,
                                               const float* __restrict__ mask,
                                               float* __restrict__ fgT,
                                               _Float16* __restrict__ bgH){
  __shared__ float tile[64][65];
  __shared__ float msh[64];
  const int z = blockIdx.y;
  const int q0 = blockIdx.x*64;
  const int tx = threadIdx.x & 63, ty = threadIdx.x >> 6;
  if(threadIdx.x < 64) msh[threadIdx.x] = mask[(size_t)z*L + q0 + threadIdx.x];
  #pragma unroll
  for(int i=0;i<16;i++){
    const int c = ty*16 + i;
    tile[c][tx] = fg[((size_t)z*64 + c)*L + q0 + tx];
  }
  __syncthreads();
  #pragma unroll
  for(int i=0;i<16;i++){
    const int q = ty*16 + i;
    fgT[((size_t)z*L + q0 + q)*64 + tx] = tile[tx][q];
  }
  const float mval = (1.0f - msh[tx])*128.0f;
  #pragma unroll
  for(int i=0;i<16;i++){
    const int c = ty*16 + i;
    bgH[((size_t)z*64 + c)*L + q0 + tx] = (_Float16)(tile[c][tx]*mval);
  }
}

// ---------------- fused builder: p1 (Bhat,Pfg) + p3 (Bhat,rn3,PfgBox) ----------------
__global__ __launch_bounds__(256) void build_all(const float* __restrict__ fgT,
                                                 const float* __restrict__ mask,
                                                 _Float16* __restrict__ BhatH1,
                                                 _Float16* __restrict__ PfgH1,
                                                 _Float16* __restrict__ BhatH3,
                                                 _Float16* __restrict__ PfgH3,
                                                 float* __restrict__ rn3){
  const int t = threadIdx.x, c = t & 63, sub = t >> 6;
  const int l = blockIdx.x*4 + sub, z = blockIdx.y;
  const float* fgz = fgT + (size_t)z*L*64;
  const float* mz  = mask + (size_t)z*L;
  const int y = l >> 6, x = l & 63;
  float Wn[5][5];
  #pragma unroll
  for(int u=0;u<5;u++){
    const int yy = y+u-2;
    #pragma unroll
    for(int v=0;v<5;v++){
      const int xx = x+v-2;
      Wn[u][v] = (yy>=0 && yy<HH && xx>=0 && xx<WW) ? fgz[(size_t)(yy*WW+xx)*64 + c] : 0.f;
    }
  }
  float m3[3][3];
  #pragma unroll
  for(int i=0;i<3;i++){
    #pragma unroll
    for(int j=0;j<3;j++){
      const int yy = y+i-1, xx = x+j-1;
      m3[i][j] = (yy>=0&&yy<HH&&xx>=0&&xx<WW) ? mz[yy*WW+xx] : 0.f;
    }
  }
  // ---- p1 ----
  {
    const float K1 = Wn[2][2]*(1.0f - m3[1][1]) + 1e-7f;
    const float ss = wave_sum(K1*K1);
    BhatH1[((size_t)z*L + l)*NC + c] = (_Float16)(K1*rsqrtf(ss));
    float s = 0.f;
    #pragma unroll
    for(int a=0;a<3;a++)
      #pragma unroll
      for(int b=0;b<3;b++) s += Wn[1+a][1+b];
    PfgH1[((size_t)z*L + l)*NC + c] = (_Float16)s;
  }
  // ---- p3 Bhat + rn3 ----
  {
    float K[9]; float ss = 0.f;
    #pragma unroll
    for(int i=0;i<3;i++)
      #pragma unroll
      for(int j=0;j<3;j++){
        const float v = Wn[1+i][1+j]*(1.0f - m3[i][j]) + 1e-7f;
        K[i*3+j] = v; ss += v*v;
      }
    ss = wave_sum(ss);
    const float rn = rsqrtf(ss);
    _Float16* outp = BhatH3 + ((size_t)z*L + l)*D3 + c*9;
    #pragma unroll
    for(int k=0;k<9;k++) outp[k] = (_Float16)(K[k]*rn);
    if(c==0) rn3[(size_t)z*L + l] = rn;
  }
  // ---- p3 PfgBox ----
  {
    const bool dyok[3] = { y-1>=0, true, y+1<HH };
    const bool dxok[3] = { x-1>=0, true, x+1<WW };
    _Float16* outp = PfgH3 + ((size_t)z*L + l)*D3 + c*9;
    #pragma unroll
    for(int i=0;i<3;i++)
      #pragma unroll
      for(int j=0;j<3;j++){
        float acc = 0.f;
        #pragma unroll
        for(int a=0;a<3;a++){
          if(!dyok[a]) continue;
          #pragma unroll
          for(int b=0;b<3;b++){
            if(!dxok[b]) continue;
            acc += Wn[i+a][j+b];
          }
        }
        outp[i*3+j] = (_Float16)acc;
      }
  }
}

__global__ __launch_bounds__(256) void transpose_h(const ushort* __restrict__ src,
                                                   ushort* __restrict__ dst,
                                                   int C, size_t sSz, size_t sDz){
  __shared__ ushort tile[64][65];
  const int z = blockIdx.z;
  src += z*sSz; dst += z*sDz;
  const int bc = blockIdx.x*64, br = blockIdx.y*64;
  const int tx = threadIdx.x & 15, ty = threadIdx.x >> 4;
  #pragma unroll
  for(int i=0;i<4;i++){
    const ushort4 v = *(const ushort4*)(src + (size_t)(br+ty+16*i)*C + bc + tx*4);
    tile[ty+16*i][tx*4+0] = v.x;
    tile[ty+16*i][tx*4+1] = v.y;
    tile[ty+16*i][tx*4+2] = v.z;
    tile[ty+16*i][tx*4+3] = v.w;
  }
  __syncthreads();
  #pragma unroll
  for(int i=0;i<4;i++){
    ushort4 o;
    o.x = tile[tx*4+0][ty+16*i];
    o.y = tile[tx*4+1][ty+16*i];
    o.z = tile[tx*4+2][ty+16*i];
    o.w = tile[tx*4+3][ty+16*i];
    *(ushort4*)(dst + (size_t)(bc+ty+16*i)*L + br + tx*4) = o;
  }
}

// ---------------- barrier-free per-wave flash attention (p=1) ----------------
// Partials stored RAW in fp16 (|O| <= Lsum*max|V| <= 256; fp16 rel err 5e-4).
__global__ __launch_bounds__(256) void flash_p1(const _Float16* __restrict__ Q,
                                                const _Float16* __restrict__ Km,
                                                const _Float16* __restrict__ Vt,
                                                _Float16* __restrict__ Op,
                                                float* __restrict__ Ml,
                                                float* __restrict__ Ll){
  __shared__ _Float16 Qs[QB*64];
  __shared__ _Float16 KsA[4][QB*64];
  __shared__ _Float16 VsA[4][64*32];
  __shared__ _Float16 PsA[4][QB*32];
  __shared__ float    FwA[4][QB];
  const int z = blockIdx.z, sp = blockIdx.y, q0 = blockIdx.x*QB;
  const int t = threadIdx.x, lane = t&63, wave = t>>6;
  const int r16 = lane&15, g4 = lane>>4;
  _Float16* Ks = KsA[wave];
  _Float16* Vs = VsA[wave];
  _Float16* Ps = PsA[wave];
  float* Fw = FwA[wave];
  {
    const int row = t>>3, ch = t&7;
    gload16(Q + ((size_t)z*L + q0 + row)*64 + ((ch ^ (row&7))<<3), (char*)Qs + t*16);
  }
  asm volatile("s_waitcnt vmcnt(0)" ::: "memory");
  __syncthreads();

  float Mreg[2] = {-3.0e38f, -3.0e38f};
  float Lreg[2] = {0.f, 0.f};
  f32x4 accO[2][4] = {};

  for(int tt=0; tt<8; ++tt){
    const int lbase = sp*1024 + tt*128 + wave*32;
    #pragma unroll
    for(int u=0;u<4;u++){
      const int row = u*8 + (lane>>3), ch = lane&7;
      gload16(Km + ((size_t)z*L + lbase + row)*64 + ((ch ^ (row&7))<<3),
              (char*)Ks + u*1024 + lane*16);
    }
    #pragma unroll
    for(int u=0;u<4;u++){
      const int cst = u*16 + (lane>>2), slot = lane&3;
      gload16(Vt + ((size_t)z*64 + cst)*L + lbase + ((slot ^ (cst&3))<<3),
              (char*)Vs + u*1024 + lane*16);
    }
    asm volatile("s_waitcnt vmcnt(0)" ::: "memory");
    __builtin_amdgcn_sched_barrier(0);
    f32x4 acc[2][2] = {};
    #pragma unroll
    for(int kk=0;kk<2;kk++){
      f16x8 af[2], bf[2];
      #pragma unroll
      for(int i=0;i<2;i++){
        const int row = i*16 + r16;
        af[i] = *(const f16x8*)((const char*)Ks + (((row<<7) + kk*64 + (g4<<4)) ^ ((row&7)<<4)));
      }
      #pragma unroll
      for(int j=0;j<2;j++){
        const int row = j*16 + r16;
        bf[j] = *(const f16x8*)((const char*)Qs + (((row<<7) + kk*64 + (g4<<4)) ^ ((row&7)<<4)));
      }
      #pragma unroll
      for(int i=0;i<2;i++)
        #pragma unroll
        for(int j=0;j<2;j++)
          acc[i][j] = __builtin_amdgcn_mfma_f32_16x16x32_f16(af[i], bf[j], acc[i][j], 0,0,0);
    }
    float fs[2];
    #pragma unroll
    for(int j=0;j<2;j++){
      float mv = -3.0e38f;
      #pragma unroll
      for(int i=0;i<2;i++)
        #pragma unroll
        for(int r=0;r<4;r++) mv = fmaxf(mv, acc[i][j][r]);
      mv = fmaxf(mv, __shfl_xor(mv, 16));
      mv = fmaxf(mv, __shfl_xor(mv, 32));
      const float mnew = fmaxf(Mreg[j], mv);
      fs[j] = __expf(Mreg[j] - mnew);
      Mreg[j] = mnew;
      float ps = 0.f;
      const int q = j*16 + r16;
      #pragma unroll
      for(int i=0;i<2;i++){
        f16x4 ph;
        #pragma unroll
        for(int r=0;r<4;r++){
          const float p = __expf(acc[i][j][r] - mnew);
          ps += p; ph[r] = (_Float16)p;
        }
        *(f16x4*)((char*)Ps + (q<<6) + ((i*32 + g4*8) ^ ((q&3)<<4))) = ph;
      }
      ps += __shfl_xor(ps, 16);
      ps += __shfl_xor(ps, 32);
      Lreg[j] = Lreg[j]*fs[j] + ps;
    }
    if(g4==0){ Fw[r16] = fs[0]; Fw[16+r16] = fs[1]; }
    #pragma unroll
    for(int qb=0;qb<2;qb++){
      float f4[4];
      #pragma unroll
      for(int r=0;r<4;r++) f4[r] = Fw[qb*16 + g4*4 + r];
      #pragma unroll
      for(int cb=0;cb<4;cb++)
        #pragma unroll
        for(int r=0;r<4;r++) accO[qb][cb][r] *= f4[r];
    }
    #pragma unroll
    for(int qb=0;qb<2;qb++){
      const int qrow = qb*16 + r16;
      const f16x8 af = *(const f16x8*)((const char*)Ps + (qrow<<6) + ((g4<<4) ^ ((qrow&3)<<4)));
      #pragma unroll
      for(int cb=0;cb<4;cb++){
        const int crow = cb*16 + r16;
        const f16x8 bf = *(const f16x8*)((const char*)Vs + (crow<<6) + ((g4<<4) ^ ((crow&3)<<4)));
        accO[qb][cb] = __builtin_amdgcn_mfma_f32_16x16x32_f16(af, bf, accO[qb][cb], 0,0,0);
      }
    }
  }
  const int sidx = (z*NSPLIT + sp)*4 + wave;
  #pragma unroll
  for(int qb=0;qb<2;qb++){
    #pragma unroll
    for(int cb=0;cb<4;cb++){
      #pragma unroll
      for(int r=0;r<4;r++){
        const int ql = qb*16 + g4*4 + r;
        Op[((size_t)sidx*L + q0 + ql)*64 + cb*16 + r16] = (_Float16)accO[qb][cb][r];
      }
    }
  }
  if(g4==0){
    Ml[(size_t)sidx*L + q0 + r16]      = Mreg[0];
    Ml[(size_t)sidx*L + q0 + 16 + r16] = Mreg[1];
    Ll[(size_t)sidx*L + q0 + r16]      = Lreg[0];
    Ll[(size_t)sidx*L + q0 + 16 + r16] = Lreg[1];
  }
}

// ---------------- QKT GEMM: fp16 output, 2D XCD-region swizzle ----------------
template<int OM, int KS>
__global__ __launch_bounds__(256, 3) void gemm_h16(const _Float16* __restrict__ A, int lda, size_t sAz,
                                                   const _Float16* __restrict__ B, int ldb, size_t sBz,
                                                   void* __restrict__ C, int ldc, size_t sCz,
                                                   int K, size_t sPart){
  __shared__ _Float16 sh[16384];   // As(8192) + Bs(8192) = 32768 B total
  _Float16* As = sh;
  _Float16* Bs = sh + 8192;
  const int zz = blockIdx.z;
  const int z = zz / KS, ks = zz % KS;
  const int Kp = K / KS;
  A += (size_t)z*sAz + (size_t)ks*Kp;
  B += (size_t)z*sBz + (size_t)ks*Kp;
  int bxi = blockIdx.x, byi = blockIdx.y;
  if(OM==2){
    const int i = byi*32 + bxi;
    const int xcd = i & 7, tt = (i >> 3) & 127;
    byi = 8*(xcd & 3) + (tt & 7);
    bxi = 16*(xcd >> 2) + (tt >> 3);
  }
  const int bm = byi*128, bn = bxi*128;
  const int t = threadIdx.x, lane = t & 63, wave = t >> 6;
  const int wr = wave >> 1, wc = wave & 1;
  const int r16 = lane & 15, g4 = lane >> 4;
  const int srow = t >> 3;
  const int schunk = t & 7;
  f32x4 acc[4][4] = {};
  for(int k0=0;k0<Kp;k0+=64){
    #pragma unroll
    for(int u=0;u<4;u++){
      const int rowA = u*32 + srow;
      const int colh = ((schunk ^ (rowA & 7)) << 3);
      gload16(A + (size_t)(bm+rowA)*lda + k0 + colh, (char*)As + u*4096 + wave*1024);
      gload16(B + (size_t)(bn+rowA)*ldb + k0 + colh, (char*)Bs + u*4096 + wave*1024);
    }
    __syncthreads();
    #pragma unroll
    for(int kk=0;kk<2;kk++){
      f16x8 af[4], bf[4];
      #pragma unroll
      for(int i=0;i<4;i++){
        const int row = wr*64 + i*16 + r16;
        const int off = ((row<<7) + kk*64 + (g4<<4)) ^ ((row&7)<<4);
        af[i] = *(const f16x8*)((const char*)As + off);
      }
      #pragma unroll
      for(int j=0;j<4;j++){
        const int row = wc*64 + j*16 + r16;
        const int off = ((row<<7) + kk*64 + (g4<<4)) ^ ((row&7)<<4);
        bf[j] = *(const f16x8*)((const char*)Bs + off);
      }
      #pragma unroll
      for(int i=0;i<4;i++)
        #pragma unroll
        for(int j=0;j<4;j++)
          acc[i][j] = __builtin_amdgcn_mfma_f32_16x16x32_f16(af[i], bf[j], acc[i][j], 0, 0, 0);
    }
    __syncthreads();
  }
  // two-half LDS-transpose fp16 epilogue (reuses As/Bs space)
  _Float16* Cz = (_Float16*)C + (size_t)z*sCz;
  #pragma unroll
  for(int h=0; h<2; ++h){
    __syncthreads();
    if(wr == h){
      #pragma unroll
      for(int i=0;i<4;i++){
        const int row0 = i*16 + g4*4;
        #pragma unroll
        for(int j=0;j<4;j++){
          const int col = wc*64 + j*16 + r16;
          #pragma unroll
          for(int r=0;r<4;r++)
            sh[(row0+r)*136 + col] = (_Float16)acc[i][j][r];
        }
      }
    }
    __syncthreads();
    #pragma unroll
    for(int k=0;k<4;k++){
      const int row = k*16 + (t>>4);
      const int cg = (t&15)*8;
      const f16x8 v = *(const f16x8*)(sh + row*136 + cg);
      *(f16x8*)(Cz + (size_t)(bm + h*64 + row)*ldc + bn + cg) = v;
    }
  }
}

// ---------------- PV GEMM: 128x64 tile (B has only 64 rows), fp16 split-K partials ----
// A = DxB [z][L][L], B = bgH [z][64][L], C = Cp16 [ks][z][L][64]. KS=8 fixed.
__global__ __launch_bounds__(256, 3) void gemm_pv64(const _Float16* __restrict__ A,
                                                    const _Float16* __restrict__ B,
                                                    _Float16* __restrict__ C,
                                                    size_t sPart){
  __shared__ _Float16 sh[12288];   // As 16KB + Bs 8KB = 24KB
  _Float16* As = sh;
  _Float16* Bs = sh + 8192;
  const int zz = blockIdx.z;       // z*8 + ks
  const int z = zz >> 3, ks = zz & 7;
  const int Kp = L/8;              // 512
  const _Float16* Az = A + (size_t)z*L*L + (size_t)ks*Kp;
  const _Float16* Bz = B + (size_t)z*64*L + (size_t)ks*Kp;
  const int bm = blockIdx.y*128;
  const int t = threadIdx.x, lane = t&63, wave = t>>6;
  const int r16 = lane&15, g4 = lane>>4;
  const int srow = t>>3, schunk = t&7;
  f32x4 acc[2][4] = {};
  for(int k0=0;k0<Kp;k0+=64){
    #pragma unroll
    for(int u=0;u<4;u++){
      const int rowA = u*32 + srow;
      const int colh = ((schunk ^ (rowA & 7)) << 3);
      gload16(Az + (size_t)(bm+rowA)*L + k0 + colh, (char*)As + u*4096 + wave*1024);
    }
    #pragma unroll
    for(int u=0;u<2;u++){
      const int rowB = u*32 + srow;
      const int colh = ((schunk ^ (rowB & 7)) << 3);
      gload16(Bz + (size_t)rowB*L + k0 + colh, (char*)Bs + u*4096 + wave*1024);
    }
    __syncthreads();
    #pragma unroll
    for(int kk=0;kk<2;kk++){
      f16x8 af[2], bf[4];
      #pragma unroll
      for(int i=0;i<2;i++){
        const int row = wave*32 + i*16 + r16;
        const int off = ((row<<7) + kk*64 + (g4<<4)) ^ ((row&7)<<4);
        af[i] = *(const f16x8*)((const char*)As + off);
      }
      #pragma unroll
      for(int j=0;j<4;j++){
        const int row = j*16 + r16;
        const int off = ((row<<7) + kk*64 + (g4<<4)) ^ ((row&7)<<4);
        bf[j] = *(const f16x8*)((const char*)Bs + off);
      }
      #pragma unroll
      for(int i=0;i<2;i++)
        #pragma unroll
        for(int j=0;j<4;j++)
          acc[i][j] = __builtin_amdgcn_mfma_f32_16x16x32_f16(af[i], bf[j], acc[i][j], 0, 0, 0);
    }
    __syncthreads();
  }
  // fp16 epilogue: acc -> sh[128][72] -> coalesced f16x8 stores (ldc = 64)
  #pragma unroll
  for(int i=0;i<2;i++){
    const int row0 = wave*32 + i*16 + g4*4;
    #pragma unroll
    for(int j=0;j<4;j++){
      const int col = j*16 + r16;
      #pragma unroll
      for(int r=0;r<4;r++)
        sh[(row0+r)*72 + col] = (_Float16)acc[i][j][r];
    }
  }
  __syncthreads();
  _Float16* Cz = C + (size_t)ks*sPart + (size_t)z*L*64;
  #pragma unroll
  for(int it=0; it<4; ++it){
    const int row = it*32 + (t>>3);
    const int cg = (t&7)*8;
    const f16x8 v = *(const f16x8*)(sh + row*72 + cg);
    *(f16x8*)(Cz + (size_t)(bm+row)*64 + cg) = v;
  }
}

__global__ __launch_bounds__(256) void softmax_rn(_Float16* __restrict__ S,
                                                  const float* __restrict__ rn3,
                                                  float* __restrict__ Tq){
  __shared__ float red[4];
  const int q = blockIdx.x, z = blockIdx.y, t = threadIdx.x;
  _Float16* p = S + ((size_t)z*L + q)*L;
  float v[16];
  {
    const f16x8 a = *(const f16x8*)(p + t*16);
    const f16x8 b = *(const f16x8*)(p + t*16 + 8);
    #pragma unroll
    for(int i=0;i<8;i++){ v[i] = (float)a[i]; v[8+i] = (float)b[i]; }
  }
  float mx = -3.0e38f;
  #pragma unroll
  for(int i=0;i<16;i++) mx = fmaxf(mx, v[i]);
  mx = wave_max(mx);
  if((t&63)==0) red[t>>6]=mx;
  __syncthreads();
  mx = fmaxf(fmaxf(red[0],red[1]), fmaxf(red[2],red[3]));
  __syncthreads();
  float s = 0.f;
  #pragma unroll
  for(int i=0;i<16;i++){ v[i] = __expf(v[i]-mx); s += v[i]; }
  s = wave_sum(s);
  if((t&63)==0) red[t>>6]=s;
  __syncthreads();
  s = red[0]+red[1]+red[2]+red[3];
  __syncthreads();
  const float inv = 1.0f/s;
  const float* rnz = rn3 + (size_t)z*L + t*16;
  float T = 0.f;
  f16x8 a, b;
  #pragma unroll
  for(int i=0;i<8;i++){
    const float w0 = v[i]*inv*rnz[i];
    const float w1 = v[8+i]*inv*rnz[8+i];
    T += w0 + w1;
    a[i] = (_Float16)(w0*ASCALE);
    b[i] = (_Float16)(w1*ASCALE);
  }
  *(f16x8*)(p + t*16) = a;
  *(f16x8*)(p + t*16 + 8) = b;
  T = wave_sum(T);
  if((t&63)==0) red[t>>6]=T;
  __syncthreads();
  if(t==0) Tq[(size_t)z*L + q] = red[0]+red[1]+red[2]+red[3];
}

// ---------------- 9-tap diagonal stencil, half-width staged ----------------
__global__ __launch_bounds__(256) void d9_pass(const _Float16* __restrict__ in,
                                               _Float16* __restrict__ out){
  __shared__ _Float16 rows[9*D9W];
  const int bx = blockIdx.x, by = blockIdx.y, t = threadIdx.x;
  const int a = (bx&7)*512 + (bx>>3);
  const int z = by & 1, h = by >> 1;
  const int cbase = h*2048 - 72;
  const int ya = a>>6, xa = a&63;
  const int DY[9] = {-1,-1,-1, 0,0,0, 1,1,1};
  const int DX[9] = {-1, 0, 1,-1,0,1,-1,0,1};
  bool vr[9];
  #pragma unroll
  for(int k=0;k<9;k++){
    const int yy = ya + DY[k], xx = xa + DX[k];
    vr[k] = (yy>=0 && yy<64 && xx>=0 && xx<64);
    if(vr[k]){
      const _Float16* src = in + ((size_t)z*L + a + DY[k]*64 + DX[k])*L;
      int g0 = cbase + t*8;
      g0 = g0 < 0 ? 0 : g0;
      gload16(src + g0, (char*)rows + k*(D9W*2) + t*16);
      const int g1 = cbase + (256+t)*8;
      if(t < 18 && g1 < L)
        gload16(src + g1, (char*)rows + k*(D9W*2) + 4096 + t*16);
    }
  }
  __syncthreads();
  const int m0 = h*2048 + t*8;
  const int ym = m0>>6, x0 = m0&63;
  float o[8] = {0,0,0,0,0,0,0,0};
  #pragma unroll
  for(int k=0;k<9;k++){
    const int D = DY[k]*64 + DX[k];
    const bool vy = vr[k] && ((unsigned)(ym + DY[k]) < 64u);
    if(!vy) continue;
    const int r = ((D % 8) + 8) % 8;
    const int loff = t*8 + 72 + D - r;
    const _Float16* p = rows + k*D9W + loff;
    _Float16 buf[16];
    *(f16x8*)(buf)   = *(const f16x8*)(p);
    *(f16x8*)(buf+8) = *(const f16x8*)(p+8);
    #pragma unroll
    for(int i=0;i<8;i++){
      const bool vx = (unsigned)(x0 + i + DX[k]) < 64u;
      o[i] += vx ? (float)buf[r + i] : 0.f;
    }
  }
  f16x8 w0;
  #pragma unroll
  for(int i=0;i<8;i++) w0[i] = (_Float16)o[i];
  *(f16x8*)(out + ((size_t)z*L + a)*L + m0) = w0;
}

// ---------------- fused epilogue: flash combine + p3 scatter + SE partials ----------
__global__ __launch_bounds__(256) void epilogue_qc(const _Float16* __restrict__ Op,
                                                   const float* __restrict__ Ml,
                                                   const float* __restrict__ Ll,
                                                   const _Float16* __restrict__ Cp,
                                                   const float* __restrict__ Tq,
                                                   const float* __restrict__ fgT,
                                                   const float* __restrict__ mask,
                                                   float* __restrict__ outs,
                                                   float* __restrict__ part,
                                                   size_t sPart){
  __shared__ float ps[4][128];
  const int z = blockIdx.y, t = threadIdx.x;
  const int sub = t >> 6;
  const int q = blockIdx.x*4 + sub, c = t & 63;
  const float m = mask[(size_t)z*L + q];
  const float f = fgT[((size_t)z*L + q)*64 + c];
  float o1, o3;
  // ---- p1: combine 16 raw fp16 flash partial sets ----
  {
    float mv[16];
    float ms = -3.0e38f;
    #pragma unroll
    for(int s=0;s<16;s++){
      mv[s] = Ml[(size_t)(z*16+s)*L + q];
      ms = fmaxf(ms, mv[s]);
    }
    float acc = 0.f, Lt = 0.f;
    #pragma unroll
    for(int s=0;s<16;s++){
      const float w0 = __expf(mv[s] - ms);
      acc += w0 * (float)Op[((size_t)(z*16+s)*L + q)*64 + c];
      Lt  += w0 * Ll[(size_t)(z*16+s)*L + q];
    }
    const float o = acc/Lt;
    o1 = o*m + f*(1.0f-m);
    outs[((size_t)z*L + q)*128 + c] = o1;
  }
  // ---- p3: split-K reduce (stride 64) + eps + mask mix ----
  {
    const int y = q >> 6, x = q & 63;
    const size_t idx = ((size_t)z*L + q)*64 + c;
    float rec = 0.f;
    #pragma unroll
    for(int k=0;k<8;k++) rec += (float)Cp[(size_t)k*sPart + idx];
    float tb = 0.f;
    #pragma unroll
    for(int dy=-1;dy<=1;dy++){
      const int yy = y+dy;
      if(yy<0||yy>=64) continue;
      #pragma unroll
      for(int dx=-1;dx<=1;dx++){
        const int xx = x+dx;
        if(xx<0||xx>=64) continue;
        tb += Tq[(size_t)z*L + yy*64+xx];
      }
    }
    rec += 1e-7f*tb;
    o3 = rec*(m*(1.0f/9.0f)) + f*(1.0f-m);
    outs[((size_t)z*L + q)*128 + 64 + c] = o3;
  }
  // ---- SE channel partials ----
  ps[sub][c] = o1;
  ps[sub][64 + c] = o3;
  __syncthreads();
  if(t < 128){
    const float s = ps[0][t] + ps[1][t] + ps[2][t] + ps[3][t];
    part[((size_t)z*1024 + blockIdx.x)*128 + t] = s;
  }
}

// ---------------- SE MLP (512 threads) ----------------
__global__ __launch_bounds__(512) void se_mlp(const float* __restrict__ part,
                                              const float* __restrict__ W1, const float* __restrict__ b1,
                                              const float* __restrict__ W2, const float* __restrict__ b2,
                                              float* __restrict__ g){
  __shared__ float red[4][128];
  __shared__ float s[128], h[128];
  const int z = blockIdx.x, t = threadIdx.x;
  const int ch = t & 127, sl = t >> 7;
  float a0 = 0.f;
  for(int j=sl*256; j<(sl+1)*256; ++j)
    a0 += part[((size_t)z*1024 + j)*128 + ch];
  red[sl][ch] = a0;
  __syncthreads();
  if(t < 128) s[t] = (red[0][t]+red[1][t]+red[2][t]+red[3][t])*(1.0f/4096.0f);
  __syncthreads();
  if(t < 128){
    float a = b1[t];
    const float* w = W1 + (size_t)t*128;
    for(int j=0;j<128;j++) a = fmaf(w[j], s[j], a);
    h[t] = fmaxf(a, 0.f);
  }
  __syncthreads();
  if(t < 128){
    float o = b2[t];
    const float* w = W2 + (size_t)t*128;
    for(int j=0;j<128;j++) o = fmaf(w[j], h[j], o);
    g[z*128+t] = 1.0f/(1.0f + __expf(-o));
  }
}

// ---------------- combiner: LDS-tiled 1x1 conv — outs read ONCE ----------------
__global__ __launch_bounds__(256) void combiner(const float* __restrict__ outs,
                                                const float* __restrict__ g,
                                                const float* __restrict__ Wc,
                                                const float* __restrict__ bc,
                                                float* __restrict__ out){
  __shared__ float sc[128][33];          // [ch][qi], +1 pad -> conflict-free reads
  const int z = blockIdx.y, q0 = blockIdx.x*32, t = threadIdx.x;
  const float* gz = g + z*128;
  #pragma unroll
  for(int it=0; it<4; ++it){
    const int qi = it*8 + (t>>5);
    const int c4 = (t&31)*4;
    const float4 v = *(const float4*)(outs + ((size_t)z*L + q0 + qi)*128 + c4);
    sc[c4+0][qi] = v.x*gz[c4+0];
    sc[c4+1][qi] = v.y*gz[c4+1];
    sc[c4+2][qi] = v.z*gz[c4+2];
    sc[c4+3][qi] = v.w*gz[c4+3];
  }
  __syncthreads();
  const int qi = t & 31, ob = t >> 5;
  float acc[8];
  #pragma unroll
  for(int k=0;k<8;k++) acc[k] = bc[ob*8+k];
  for(int ch=0; ch<128; ++ch){
    const float v = sc[ch][qi];
    #pragma unroll
    for(int k=0;k<8;k++)
      acc[k] = fmaf(v, Wc[(size_t)(ob*8+k)*128 + ch], acc[k]);
  }
  #pragma unroll
  for(int k=0;k<8;k++){
    const int o = ob*8 + k;
    out[((size_t)z*64 + o)*L + q0 + qi] = acc[k];
  }
}

extern "C" void kernel_launch(void* const* d_in, const int* in_sizes, int n_in,
                              void* d_out, int out_size, void* d_ws, size_t ws_size,
                              hipStream_t stream){
  const float* fg   = (const float*)d_in[0];
  const float* mask = (const float*)d_in[1];
  const float* W1   = (const float*)d_in[2];
  const float* b1   = (const float*)d_in[3];
  const float* W2   = (const float*)d_in[4];
  const float* b2   = (const float*)d_in[5];
  const float* Wc   = (const float*)d_in[6];
  const float* bc   = (const float*)d_in[7];
  float* out = (float*)d_out;

  char* w = (char*)d_ws;
  size_t off = 0;
  auto alloc = [&](size_t bytes)->void*{
    void* p = (void*)(w + off);
    off += (bytes + 255) & ~(size_t)255;
    return p;
  };
  _Float16* S    = (_Float16*)alloc(2ull*L*L*2);   // p3 scores / A''
  _Float16* DxB  = (_Float16*)alloc(2ull*L*L*2);   // d9 output G
  _Float16* Cp16 = (_Float16*)alloc(8ull*2*L*64*2); // fp16 split-K partials (N=64)
  float* outs  = (float*)alloc(2ull*L*128*4);
  float* fgT   = (float*)alloc(2ull*L*64*4);
  _Float16* BhatH1 = (_Float16*)alloc(2ull*L*64*2);
  _Float16* BhatT1 = (_Float16*)alloc(2ull*64*L*2);
  _Float16* PfgH1  = (_Float16*)alloc(2ull*L*64*2);
  _Float16* BhatH3 = (_Float16*)alloc(2ull*L*D3*2);
  _Float16* PfgH3  = (_Float16*)alloc(2ull*L*D3*2);
  _Float16* bgH    = (_Float16*)alloc(2ull*64*L*2);
  _Float16* Opb = (_Float16*)alloc((size_t)32*L*64*2);  // raw fp16 flash partials
  float* Mlb  = (float*)alloc((size_t)32*L*4);
  float* Llb  = (float*)alloc((size_t)32*L*4);
  float* rn3v = (float*)alloc(2ull*L*4);
  float* Tq   = (float*)alloc(2ull*L*4);
  float* part = (float*)alloc(2ull*1024*128*4);
  float* gbuf = (float*)alloc(1024);
  const size_t sPart = 2ull*L*64;   // elements per split (fp16, N=64)

  // ================= prep (fused transpose + bgH) =================
  prep_fg<<<dim3(64,2),256,0,stream>>>(fg, mask, fgT, bgH);
  build_all<<<dim3(L/4,2),256,0,stream>>>(fgT, mask, BhatH1, PfgH1, BhatH3, PfgH3, rn3v);
  transpose_h<<<dim3(1,64,2),256,0,stream>>>((const ushort*)BhatH1, (ushort*)BhatT1,
                                             64, (size_t)L*64, (size_t)64*L);

  // ================= p=1 branch (barrier-free flash, 16-way split) =================
  flash_p1<<<dim3(L/QB,NSPLIT,2),256,0,stream>>>(PfgH1, BhatH1, BhatT1, Opb, Mlb, Llb);

  // ================= p=3 branch =================
  gemm_h16<2,1><<<dim3(32,32,2),256,0,stream>>>(
      PfgH3, D3, (size_t)L*D3,
      BhatH3, D3, (size_t)L*D3,
      (void*)S, L, (size_t)L*L, D3, 0);
  softmax_rn<<<dim3(L,2),256,0,stream>>>(S, rn3v, Tq);
  d9_pass<<<dim3(L,4),256,0,stream>>>(S, DxB);
  gemm_pv64<<<dim3(1,32,16),256,0,stream>>>(DxB, bgH, Cp16, sPart);

  // ================= fused epilogue (both branches + SE partials) =================
  epilogue_qc<<<dim3(L/4,2),256,0,stream>>>(Opb, Mlb, Llb, Cp16, Tq, fgT, mask,
                                            outs, part, sPart);

  // ================= SE + combiner =================
  se_mlp<<<2,512,0,stream>>>(part, W1, b1, W2, b2, gbuf);
  combiner<<<dim3(L/32,2),256,0,stream>>>(outs, gbuf, Wc, bc, out);
}

// Round 22
// 210.430 us; speedup vs baseline: 1.2323x; 1.0376x over previous
//
#include <hip/hip_runtime.h>
#include <math.h>

#define WW 64
#define HH 64
#define L 4096
#define NC 64
#define D3 576
#define ASCALE (1.0f/128.0f)
#define QB 32
#define NSPLIT 4          // key-slices per z; 4 waves each -> 16 partial sets per z
#define D9W 2200          // staged cols per row-half (2192 used + pad)

typedef _Float16 f16x8 __attribute__((ext_vector_type(8)));
typedef _Float16 f16x4 __attribute__((ext_vector_type(4)));
typedef float    f32x4 __attribute__((ext_vector_type(4)));

__device__ __forceinline__ float wave_max(float v){
  #pragma unroll
  for(int o=32;o;o>>=1) v = fmaxf(v, __shfl_xor(v,o));
  return v;
}
__device__ __forceinline__ float wave_sum(float v){
  #pragma unroll
  for(int o=32;o;o>>=1) v += __shfl_xor(v,o);
  return v;
}
__device__ __forceinline__ void gload16(const void* g, void* l){
  __builtin_amdgcn_global_load_lds((const __attribute__((address_space(1))) unsigned int*)g,
                                   (__attribute__((address_space(3))) unsigned int*)l,
                                   16, 0, 0);
}

// ---------------- fused: fg transpose + bgH build (bgH [z][64][L]) ----------------
__global__ __launch_bounds__(256) void prep_fg(const float* __restrict__ fg,
                                               const float* __restrict__ mask,
                                               float* __restrict__ fgT,
                                               _Float16* __restrict__ bgH){
  __shared__ float tile[64][65];
  __shared__ float msh[64];
  const int z = blockIdx.y;
  const int q0 = blockIdx.x*64;
  const int tx = threadIdx.x & 63, ty = threadIdx.x >> 6;
  if(threadIdx.x < 64) msh[threadIdx.x] = mask[(size_t)z*L + q0 + threadIdx.x];
  #pragma unroll
  for(int i=0;i<16;i++){
    const int c = ty*16 + i;
    tile[c][tx] = fg[((size_t)z*64 + c)*L + q0 + tx];
  }
  __syncthreads();
  #pragma unroll
  for(int i=0;i<16;i++){
    const int q = ty*16 + i;
    fgT[((size_t)z*L + q0 + q)*64 + tx] = tile[tx][q];
  }
  const float mval = (1.0f - msh[tx])*128.0f;
  #pragma unroll
  for(int i=0;i<16;i++){
    const int c = ty*16 + i;
    bgH[((size_t)z*64 + c)*L + q0 + tx] = (_Float16)(tile[c][tx]*mval);
  }
}

// ---------------- fused builder: p1 (Bhat,Pfg) + p3 (Bhat,rn3,PfgBox) ----------------
// p3 K-layout PERMUTED: element (c,k) stored at k*64+c (coalesced lane-contiguous
// stores). Applied to BOTH BhatH3 and PfgH3 -> QKT dot product invariant.
__global__ __launch_bounds__(256) void build_all(const float* __restrict__ fgT,
                                                 const float* __restrict__ mask,
                                                 _Float16* __restrict__ BhatH1,
                                                 _Float16* __restrict__ PfgH1,
                                                 _Float16* __restrict__ BhatH3,
                                                 _Float16* __restrict__ PfgH3,
                                                 float* __restrict__ rn3){
  const int t = threadIdx.x, c = t & 63, sub = t >> 6;
  const int l = blockIdx.x*4 + sub, z = blockIdx.y;
  const float* fgz = fgT + (size_t)z*L*64;
  const float* mz  = mask + (size_t)z*L;
  const int y = l >> 6, x = l & 63;
  float Wn[5][5];
  #pragma unroll
  for(int u=0;u<5;u++){
    const int yy = y+u-2;
    #pragma unroll
    for(int v=0;v<5;v++){
      const int xx = x+v-2;
      Wn[u][v] = (yy>=0 && yy<HH && xx>=0 && xx<WW) ? fgz[(size_t)(yy*WW+xx)*64 + c] : 0.f;
    }
  }
  float m3[3][3];
  #pragma unroll
  for(int i=0;i<3;i++){
    #pragma unroll
    for(int j=0;j<3;j++){
      const int yy = y+i-1, xx = x+j-1;
      m3[i][j] = (yy>=0&&yy<HH&&xx>=0&&xx<WW) ? mz[yy*WW+xx] : 0.f;
    }
  }
  // ---- p1 ----
  {
    const float K1 = Wn[2][2]*(1.0f - m3[1][1]) + 1e-7f;
    const float ss = wave_sum(K1*K1);
    BhatH1[((size_t)z*L + l)*NC + c] = (_Float16)(K1*rsqrtf(ss));
    float s = 0.f;
    #pragma unroll
    for(int a=0;a<3;a++)
      #pragma unroll
      for(int b=0;b<3;b++) s += Wn[1+a][1+b];
    PfgH1[((size_t)z*L + l)*NC + c] = (_Float16)s;
  }
  // ---- p3 Bhat + rn3 (permuted store k*64+c) ----
  {
    float K[9]; float ss = 0.f;
    #pragma unroll
    for(int i=0;i<3;i++)
      #pragma unroll
      for(int j=0;j<3;j++){
        const float v = Wn[1+i][1+j]*(1.0f - m3[i][j]) + 1e-7f;
        K[i*3+j] = v; ss += v*v;
      }
    ss = wave_sum(ss);
    const float rn = rsqrtf(ss);
    _Float16* outp = BhatH3 + ((size_t)z*L + l)*D3;
    #pragma unroll
    for(int k=0;k<9;k++) outp[k*64 + c] = (_Float16)(K[k]*rn);
    if(c==0) rn3[(size_t)z*L + l] = rn;
  }
  // ---- p3 PfgBox (permuted store k*64+c) ----
  {
    const bool dyok[3] = { y-1>=0, true, y+1<HH };
    const bool dxok[3] = { x-1>=0, true, x+1<WW };
    _Float16* outp = PfgH3 + ((size_t)z*L + l)*D3;
    #pragma unroll
    for(int i=0;i<3;i++)
      #pragma unroll
      for(int j=0;j<3;j++){
        float acc = 0.f;
        #pragma unroll
        for(int a=0;a<3;a++){
          if(!dyok[a]) continue;
          #pragma unroll
          for(int b=0;b<3;b++){
            if(!dxok[b]) continue;
            acc += Wn[i+a][j+b];
          }
        }
        outp[(i*3+j)*64 + c] = (_Float16)acc;
      }
  }
}

__global__ __launch_bounds__(256) void transpose_h(const ushort* __restrict__ src,
                                                   ushort* __restrict__ dst,
                                                   int C, size_t sSz, size_t sDz){
  __shared__ ushort tile[64][65];
  const int z = blockIdx.z;
  src += z*sSz; dst += z*sDz;
  const int bc = blockIdx.x*64, br = blockIdx.y*64;
  const int tx = threadIdx.x & 15, ty = threadIdx.x >> 4;
  #pragma unroll
  for(int i=0;i<4;i++){
    const ushort4 v = *(const ushort4*)(src + (size_t)(br+ty+16*i)*C + bc + tx*4);
    tile[ty+16*i][tx*4+0] = v.x;
    tile[ty+16*i][tx*4+1] = v.y;
    tile[ty+16*i][tx*4+2] = v.z;
    tile[ty+16*i][tx*4+3] = v.w;
  }
  __syncthreads();
  #pragma unroll
  for(int i=0;i<4;i++){
    ushort4 o;
    o.x = tile[tx*4+0][ty+16*i];
    o.y = tile[tx*4+1][ty+16*i];
    o.z = tile[tx*4+2][ty+16*i];
    o.w = tile[tx*4+3][ty+16*i];
    *(ushort4*)(dst + (size_t)(bc+ty+16*i)*L + br + tx*4) = o;
  }
}

// ---------------- barrier-free per-wave flash attention (p=1) ----------------
__global__ __launch_bounds__(256) void flash_p1(const _Float16* __restrict__ Q,
                                                const _Float16* __restrict__ Km,
                                                const _Float16* __restrict__ Vt,
                                                _Float16* __restrict__ Op,
                                                float* __restrict__ Ml,
                                                float* __restrict__ Ll){
  __shared__ _Float16 Qs[QB*64];
  __shared__ _Float16 KsA[4][QB*64];
  __shared__ _Float16 VsA[4][64*32];
  __shared__ _Float16 PsA[4][QB*32];
  __shared__ float    FwA[4][QB];
  const int z = blockIdx.z, sp = blockIdx.y, q0 = blockIdx.x*QB;
  const int t = threadIdx.x, lane = t&63, wave = t>>6;
  const int r16 = lane&15, g4 = lane>>4;
  _Float16* Ks = KsA[wave];
  _Float16* Vs = VsA[wave];
  _Float16* Ps = PsA[wave];
  float* Fw = FwA[wave];
  {
    const int row = t>>3, ch = t&7;
    gload16(Q + ((size_t)z*L + q0 + row)*64 + ((ch ^ (row&7))<<3), (char*)Qs + t*16);
  }
  asm volatile("s_waitcnt vmcnt(0)" ::: "memory");
  __syncthreads();

  float Mreg[2] = {-3.0e38f, -3.0e38f};
  float Lreg[2] = {0.f, 0.f};
  f32x4 accO[2][4] = {};

  for(int tt=0; tt<8; ++tt){
    const int lbase = sp*1024 + tt*128 + wave*32;
    #pragma unroll
    for(int u=0;u<4;u++){
      const int row = u*8 + (lane>>3), ch = lane&7;
      gload16(Km + ((size_t)z*L + lbase + row)*64 + ((ch ^ (row&7))<<3),
              (char*)Ks + u*1024 + lane*16);
    }
    #pragma unroll
    for(int u=0;u<4;u++){
      const int cst = u*16 + (lane>>2), slot = lane&3;
      gload16(Vt + ((size_t)z*64 + cst)*L + lbase + ((slot ^ (cst&3))<<3),
              (char*)Vs + u*1024 + lane*16);
    }
    asm volatile("s_waitcnt vmcnt(0)" ::: "memory");
    __builtin_amdgcn_sched_barrier(0);
    f32x4 acc[2][2] = {};
    #pragma unroll
    for(int kk=0;kk<2;kk++){
      f16x8 af[2], bf[2];
      #pragma unroll
      for(int i=0;i<2;i++){
        const int row = i*16 + r16;
        af[i] = *(const f16x8*)((const char*)Ks + (((row<<7) + kk*64 + (g4<<4)) ^ ((row&7)<<4)));
      }
      #pragma unroll
      for(int j=0;j<2;j++){
        const int row = j*16 + r16;
        bf[j] = *(const f16x8*)((const char*)Qs + (((row<<7) + kk*64 + (g4<<4)) ^ ((row&7)<<4)));
      }
      #pragma unroll
      for(int i=0;i<2;i++)
        #pragma unroll
        for(int j=0;j<2;j++)
          acc[i][j] = __builtin_amdgcn_mfma_f32_16x16x32_f16(af[i], bf[j], acc[i][j], 0,0,0);
    }
    float fs[2];
    #pragma unroll
    for(int j=0;j<2;j++){
      float mv = -3.0e38f;
      #pragma unroll
      for(int i=0;i<2;i++)
        #pragma unroll
        for(int r=0;r<4;r++) mv = fmaxf(mv, acc[i][j][r]);
      mv = fmaxf(mv, __shfl_xor(mv, 16));
      mv = fmaxf(mv, __shfl_xor(mv, 32));
      const float mnew = fmaxf(Mreg[j], mv);
      fs[j] = __expf(Mreg[j] - mnew);
      Mreg[j] = mnew;
      float ps = 0.f;
      const int q = j*16 + r16;
      #pragma unroll
      for(int i=0;i<2;i++){
        f16x4 ph;
        #pragma unroll
        for(int r=0;r<4;r++){
          const float p = __expf(acc[i][j][r] - mnew);
          ps += p; ph[r] = (_Float16)p;
        }
        *(f16x4*)((char*)Ps + (q<<6) + ((i*32 + g4*8) ^ ((q&3)<<4))) = ph;
      }
      ps += __shfl_xor(ps, 16);
      ps += __shfl_xor(ps, 32);
      Lreg[j] = Lreg[j]*fs[j] + ps;
    }
    if(g4==0){ Fw[r16] = fs[0]; Fw[16+r16] = fs[1]; }
    #pragma unroll
    for(int qb=0;qb<2;qb++){
      float f4[4];
      #pragma unroll
      for(int r=0;r<4;r++) f4[r] = Fw[qb*16 + g4*4 + r];
      #pragma unroll
      for(int cb=0;cb<4;cb++)
        #pragma unroll
        for(int r=0;r<4;r++) accO[qb][cb][r] *= f4[r];
    }
    #pragma unroll
    for(int qb=0;qb<2;qb++){
      const int qrow = qb*16 + r16;
      const f16x8 af = *(const f16x8*)((const char*)Ps + (qrow<<6) + ((g4<<4) ^ ((qrow&3)<<4)));
      #pragma unroll
      for(int cb=0;cb<4;cb++){
        const int crow = cb*16 + r16;
        const f16x8 bf = *(const f16x8*)((const char*)Vs + (crow<<6) + ((g4<<4) ^ ((crow&3)<<4)));
        accO[qb][cb] = __builtin_amdgcn_mfma_f32_16x16x32_f16(af, bf, accO[qb][cb], 0,0,0);
      }
    }
  }
  const int sidx = (z*NSPLIT + sp)*4 + wave;
  #pragma unroll
  for(int qb=0;qb<2;qb++){
    #pragma unroll
    for(int cb=0;cb<4;cb++){
      #pragma unroll
      for(int r=0;r<4;r++){
        const int ql = qb*16 + g4*4 + r;
        Op[((size_t)sidx*L + q0 + ql)*64 + cb*16 + r16] = (_Float16)accO[qb][cb][r];
      }
    }
  }
  if(g4==0){
    Ml[(size_t)sidx*L + q0 + r16]      = Mreg[0];
    Ml[(size_t)sidx*L + q0 + 16 + r16] = Mreg[1];
    Ll[(size_t)sidx*L + q0 + r16]      = Lreg[0];
    Ll[(size_t)sidx*L + q0 + 16 + r16] = Lreg[1];
  }
}

// ---------------- QKT GEMM: fp16 output, 2D XCD-region swizzle ----------------
template<int OM, int KS>
__global__ __launch_bounds__(256, 3) void gemm_h16(const _Float16* __restrict__ A, int lda, size_t sAz,
                                                   const _Float16* __restrict__ B, int ldb, size_t sBz,
                                                   void* __restrict__ C, int ldc, size_t sCz,
                                                   int K, size_t sPart){
  __shared__ _Float16 sh[16384];
  _Float16* As = sh;
  _Float16* Bs = sh + 8192;
  const int zz = blockIdx.z;
  const int z = zz / KS, ks = zz % KS;
  const int Kp = K / KS;
  A += (size_t)z*sAz + (size_t)ks*Kp;
  B += (size_t)z*sBz + (size_t)ks*Kp;
  int bxi = blockIdx.x, byi = blockIdx.y;
  if(OM==2){
    const int i = byi*32 + bxi;
    const int xcd = i & 7, tt = (i >> 3) & 127;
    byi = 8*(xcd & 3) + (tt & 7);
    bxi = 16*(xcd >> 2) + (tt >> 3);
  }
  const int bm = byi*128, bn = bxi*128;
  const int t = threadIdx.x, lane = t & 63, wave = t >> 6;
  const int wr = wave >> 1, wc = wave & 1;
  const int r16 = lane & 15, g4 = lane >> 4;
  const int srow = t >> 3;
  const int schunk = t & 7;
  f32x4 acc[4][4] = {};
  for(int k0=0;k0<Kp;k0+=64){
    #pragma unroll
    for(int u=0;u<4;u++){
      const int rowA = u*32 + srow;
      const int colh = ((schunk ^ (rowA & 7)) << 3);
      gload16(A + (size_t)(bm+rowA)*lda + k0 + colh, (char*)As + u*4096 + wave*1024);
      gload16(B + (size_t)(bn+rowA)*ldb + k0 + colh, (char*)Bs + u*4096 + wave*1024);
    }
    __syncthreads();
    #pragma unroll
    for(int kk=0;kk<2;kk++){
      f16x8 af[4], bf[4];
      #pragma unroll
      for(int i=0;i<4;i++){
        const int row = wr*64 + i*16 + r16;
        const int off = ((row<<7) + kk*64 + (g4<<4)) ^ ((row&7)<<4);
        af[i] = *(const f16x8*)((const char*)As + off);
      }
      #pragma unroll
      for(int j=0;j<4;j++){
        const int row = wc*64 + j*16 + r16;
        const int off = ((row<<7) + kk*64 + (g4<<4)) ^ ((row&7)<<4);
        bf[j] = *(const f16x8*)((const char*)Bs + off);
      }
      #pragma unroll
      for(int i=0;i<4;i++)
        #pragma unroll
        for(int j=0;j<4;j++)
          acc[i][j] = __builtin_amdgcn_mfma_f32_16x16x32_f16(af[i], bf[j], acc[i][j], 0, 0, 0);
    }
    __syncthreads();
  }
  _Float16* Cz = (_Float16*)C + (size_t)z*sCz;
  #pragma unroll
  for(int h=0; h<2; ++h){
    __syncthreads();
    if(wr == h){
      #pragma unroll
      for(int i=0;i<4;i++){
        const int row0 = i*16 + g4*4;
        #pragma unroll
        for(int j=0;j<4;j++){
          const int col = wc*64 + j*16 + r16;
          #pragma unroll
          for(int r=0;r<4;r++)
            sh[(row0+r)*136 + col] = (_Float16)acc[i][j][r];
        }
      }
    }
    __syncthreads();
    #pragma unroll
    for(int k=0;k<4;k++){
      const int row = k*16 + (t>>4);
      const int cg = (t&15)*8;
      const f16x8 v = *(const f16x8*)(sh + row*136 + cg);
      *(f16x8*)(Cz + (size_t)(bm + h*64 + row)*ldc + bn + cg) = v;
    }
  }
}

// ---------------- PV GEMM: 128x64 tile, fp16 split-K partials ----------------
__global__ __launch_bounds__(256, 3) void gemm_pv64(const _Float16* __restrict__ A,
                                                    const _Float16* __restrict__ B,
                                                    _Float16* __restrict__ C,
                                                    size_t sPart){
  __shared__ _Float16 sh[12288];
  _Float16* As = sh;
  _Float16* Bs = sh + 8192;
  const int zz = blockIdx.z;
  const int z = zz >> 3, ks = zz & 7;
  const int Kp = L/8;
  const _Float16* Az = A + (size_t)z*L*L + (size_t)ks*Kp;
  const _Float16* Bz = B + (size_t)z*64*L + (size_t)ks*Kp;
  const int bm = blockIdx.y*128;
  const int t = threadIdx.x, lane = t&63, wave = t>>6;
  const int r16 = lane&15, g4 = lane>>4;
  const int srow = t>>3, schunk = t&7;
  f32x4 acc[2][4] = {};
  for(int k0=0;k0<Kp;k0+=64){
    #pragma unroll
    for(int u=0;u<4;u++){
      const int rowA = u*32 + srow;
      const int colh = ((schunk ^ (rowA & 7)) << 3);
      gload16(Az + (size_t)(bm+rowA)*L + k0 + colh, (char*)As + u*4096 + wave*1024);
    }
    #pragma unroll
    for(int u=0;u<2;u++){
      const int rowB = u*32 + srow;
      const int colh = ((schunk ^ (rowB & 7)) << 3);
      gload16(Bz + (size_t)rowB*L + k0 + colh, (char*)Bs + u*4096 + wave*1024);
    }
    __syncthreads();
    #pragma unroll
    for(int kk=0;kk<2;kk++){
      f16x8 af[2], bf[4];
      #pragma unroll
      for(int i=0;i<2;i++){
        const int row = wave*32 + i*16 + r16;
        const int off = ((row<<7) + kk*64 + (g4<<4)) ^ ((row&7)<<4);
        af[i] = *(const f16x8*)((const char*)As + off);
      }
      #pragma unroll
      for(int j=0;j<4;j++){
        const int row = j*16 + r16;
        const int off = ((row<<7) + kk*64 + (g4<<4)) ^ ((row&7)<<4);
        bf[j] = *(const f16x8*)((const char*)Bs + off);
      }
      #pragma unroll
      for(int i=0;i<2;i++)
        #pragma unroll
        for(int j=0;j<4;j++)
          acc[i][j] = __builtin_amdgcn_mfma_f32_16x16x32_f16(af[i], bf[j], acc[i][j], 0, 0, 0);
    }
    __syncthreads();
  }
  #pragma unroll
  for(int i=0;i<2;i++){
    const int row0 = wave*32 + i*16 + g4*4;
    #pragma unroll
    for(int j=0;j<4;j++){
      const int col = j*16 + r16;
      #pragma unroll
      for(int r=0;r<4;r++)
        sh[(row0+r)*72 + col] = (_Float16)acc[i][j][r];
    }
  }
  __syncthreads();
  _Float16* Cz = C + (size_t)ks*sPart + (size_t)z*L*64;
  #pragma unroll
  for(int it=0; it<4; ++it){
    const int row = it*32 + (t>>3);
    const int cg = (t&7)*8;
    const f16x8 v = *(const f16x8*)(sh + row*72 + cg);
    *(f16x8*)(Cz + (size_t)(bm+row)*64 + cg) = v;
  }
}

__global__ __launch_bounds__(256) void softmax_rn(_Float16* __restrict__ S,
                                                  const float* __restrict__ rn3,
                                                  float* __restrict__ Tq){
  __shared__ float red[4];
  const int q = blockIdx.x, z = blockIdx.y, t = threadIdx.x;
  _Float16* p = S + ((size_t)z*L + q)*L;
  float v[16];
  {
    const f16x8 a = *(const f16x8*)(p + t*16);
    const f16x8 b = *(const f16x8*)(p + t*16 + 8);
    #pragma unroll
    for(int i=0;i<8;i++){ v[i] = (float)a[i]; v[8+i] = (float)b[i]; }
  }
  float mx = -3.0e38f;
  #pragma unroll
  for(int i=0;i<16;i++) mx = fmaxf(mx, v[i]);
  mx = wave_max(mx);
  if((t&63)==0) red[t>>6]=mx;
  __syncthreads();
  mx = fmaxf(fmaxf(red[0],red[1]), fmaxf(red[2],red[3]));
  __syncthreads();
  float s = 0.f;
  #pragma unroll
  for(int i=0;i<16;i++){ v[i] = __expf(v[i]-mx); s += v[i]; }
  s = wave_sum(s);
  if((t&63)==0) red[t>>6]=s;
  __syncthreads();
  s = red[0]+red[1]+red[2]+red[3];
  __syncthreads();
  const float inv = 1.0f/s;
  const float* rnz = rn3 + (size_t)z*L + t*16;
  float T = 0.f;
  f16x8 a, b;
  #pragma unroll
  for(int i=0;i<8;i++){
    const float w0 = v[i]*inv*rnz[i];
    const float w1 = v[8+i]*inv*rnz[8+i];
    T += w0 + w1;
    a[i] = (_Float16)(w0*ASCALE);
    b[i] = (_Float16)(w1*ASCALE);
  }
  *(f16x8*)(p + t*16) = a;
  *(f16x8*)(p + t*16 + 8) = b;
  T = wave_sum(T);
  if((t&63)==0) red[t>>6]=T;
  __syncthreads();
  if(t==0) Tq[(size_t)z*L + q] = red[0]+red[1]+red[2]+red[3];
}

// ---------------- 9-tap diagonal stencil: 2 output rows per block ----------------
// Rows a0, a0+1 (a0 even -> same y). 12 staged rows cover both rows' 18 taps.
__global__ __launch_bounds__(256) void d9_pass(const _Float16* __restrict__ in,
                                               _Float16* __restrict__ out){
  __shared__ _Float16 rows[12*D9W];
  const int bx = blockIdx.x, by = blockIdx.y, t = threadIdx.x;
  const int p = (bx&7)*256 + (bx>>3);    // XCD-chunked pair index, bijective on [0,2048)
  const int a0 = p*2;
  const int z = by & 1, h = by >> 1;
  const int cbase = h*2048 - 72;
  const int ya = a0>>6, xa = a0&63;      // a0 even -> xa<=62, rows a0,a0+1 share y
  const int DY[9] = {-1,-1,-1, 0,0,0, 1,1,1};
  const int DX[9] = {-1, 0, 1,-1,0,1,-1,0,1};
  const int BJ[9] = {0,1,2, 4,5,6, 8,9,10};        // staged index for o=0 taps
  const int DD[12] = {-65,-64,-63,-62, -1,0,1,2, 63,64,65,66};
  bool vr[2][9];
  bool ld[12];
  #pragma unroll
  for(int j=0;j<12;j++) ld[j] = false;
  #pragma unroll
  for(int o=0;o<2;o++){
    #pragma unroll
    for(int k=0;k<9;k++){
      const int yy = ya + DY[k], xx = xa + o + DX[k];
      vr[o][k] = (yy>=0 && yy<64 && xx>=0 && xx<64);
      if(vr[o][k]) ld[BJ[k]+o] = true;
    }
  }
  #pragma unroll
  for(int j=0;j<12;j++){
    if(ld[j]){   // block-uniform -> full wave exec inside
      const _Float16* src = in + ((size_t)z*L + a0 + DD[j])*L;
      int g0 = cbase + t*8;
      g0 = g0 < 0 ? 0 : g0;
      gload16(src + g0, (char*)rows + j*(D9W*2) + t*16);
      const int g1 = cbase + (256+t)*8;
      if(t < 18 && g1 < L)
        gload16(src + g1, (char*)rows + j*(D9W*2) + 4096 + t*16);
    }
  }
  __syncthreads();
  const int m0 = h*2048 + t*8;
  const int ym = m0>>6, x0 = m0&63;
  #pragma unroll
  for(int o=0;o<2;o++){
    float acc[8] = {0,0,0,0,0,0,0,0};
    #pragma unroll
    for(int k=0;k<9;k++){
      const int D = DY[k]*64 + DX[k];
      const bool vy = vr[o][k] && ((unsigned)(ym + DY[k]) < 64u);
      if(!vy) continue;
      const int r = ((D % 8) + 8) % 8;
      const int loff = t*8 + 72 + D - r;
      const _Float16* pp = rows + (BJ[k]+o)*D9W + loff;
      _Float16 buf[16];
      *(f16x8*)(buf)   = *(const f16x8*)(pp);
      *(f16x8*)(buf+8) = *(const f16x8*)(pp+8);
      #pragma unroll
      for(int i=0;i<8;i++){
        const bool vx = (unsigned)(x0 + i + DX[k]) < 64u;
        acc[i] += vx ? (float)buf[r + i] : 0.f;
      }
    }
    f16x8 w0;
    #pragma unroll
    for(int i=0;i<8;i++) w0[i] = (_Float16)acc[i];
    *(f16x8*)(out + ((size_t)z*L + a0 + o)*L + m0) = w0;
  }
}

// ---------------- fused epilogue: flash combine + p3 scatter + SE partials ----------
__global__ __launch_bounds__(256) void epilogue_qc(const _Float16* __restrict__ Op,
                                                   const float* __restrict__ Ml,
                                                   const float* __restrict__ Ll,
                                                   const _Float16* __restrict__ Cp,
                                                   const float* __restrict__ Tq,
                                                   const float* __restrict__ fgT,
                                                   const float* __restrict__ mask,
                                                   float* __restrict__ outs,
                                                   float* __restrict__ part,
                                                   size_t sPart){
  __shared__ float ps[4][128];
  const int z = blockIdx.y, t = threadIdx.x;
  const int sub = t >> 6;
  const int q = blockIdx.x*4 + sub, c = t & 63;
  const float m = mask[(size_t)z*L + q];
  const float f = fgT[((size_t)z*L + q)*64 + c];
  float o1, o3;
  // ---- p1: combine 16 raw fp16 flash partial sets ----
  {
    float mv[16];
    float ms = -3.0e38f;
    #pragma unroll
    for(int s=0;s<16;s++){
      mv[s] = Ml[(size_t)(z*16+s)*L + q];
      ms = fmaxf(ms, mv[s]);
    }
    float acc = 0.f, Lt = 0.f;
    #pragma unroll
    for(int s=0;s<16;s++){
      const float w0 = __expf(mv[s] - ms);
      acc += w0 * (float)Op[((size_t)(z*16+s)*L + q)*64 + c];
      Lt  += w0 * Ll[(size_t)(z*16+s)*L + q];
    }
    const float o = acc/Lt;
    o1 = o*m + f*(1.0f-m);
    outs[((size_t)z*L + q)*128 + c] = o1;
  }
  // ---- p3: split-K reduce (stride 64) + eps + mask mix ----
  {
    const int y = q >> 6, x = q & 63;
    const size_t idx = ((size_t)z*L + q)*64 + c;
    float rec = 0.f;
    #pragma unroll
    for(int k=0;k<8;k++) rec += (float)Cp[(size_t)k*sPart + idx];
    float tb = 0.f;
    #pragma unroll
    for(int dy=-1;dy<=1;dy++){
      const int yy = y+dy;
      if(yy<0||yy>=64) continue;
      #pragma unroll
      for(int dx=-1;dx<=1;dx++){
        const int xx = x+dx;
        if(xx<0||xx>=64) continue;
        tb += Tq[(size_t)z*L + yy*64+xx];
      }
    }
    rec += 1e-7f*tb;
    o3 = rec*(m*(1.0f/9.0f)) + f*(1.0f-m);
    outs[((size_t)z*L + q)*128 + 64 + c] = o3;
  }
  // ---- SE channel partials ----
  ps[sub][c] = o1;
  ps[sub][64 + c] = o3;
  __syncthreads();
  if(t < 128){
    const float s = ps[0][t] + ps[1][t] + ps[2][t] + ps[3][t];
    part[((size_t)z*1024 + blockIdx.x)*128 + t] = s;
  }
}

// ---------------- SE MLP (512 threads) ----------------
__global__ __launch_bounds__(512) void se_mlp(const float* __restrict__ part,
                                              const float* __restrict__ W1, const float* __restrict__ b1,
                                              const float* __restrict__ W2, const float* __restrict__ b2,
                                              float* __restrict__ g){
  __shared__ float red[4][128];
  __shared__ float s[128], h[128];
  const int z = blockIdx.x, t = threadIdx.x;
  const int ch = t & 127, sl = t >> 7;
  float a0 = 0.f;
  for(int j=sl*256; j<(sl+1)*256; ++j)
    a0 += part[((size_t)z*1024 + j)*128 + ch];
  red[sl][ch] = a0;
  __syncthreads();
  if(t < 128) s[t] = (red[0][t]+red[1][t]+red[2][t]+red[3][t])*(1.0f/4096.0f);
  __syncthreads();
  if(t < 128){
    float a = b1[t];
    const float* w = W1 + (size_t)t*128;
    for(int j=0;j<128;j++) a = fmaf(w[j], s[j], a);
    h[t] = fmaxf(a, 0.f);
  }
  __syncthreads();
  if(t < 128){
    float o = b2[t];
    const float* w = W2 + (size_t)t*128;
    for(int j=0;j<128;j++) o = fmaf(w[j], h[j], o);
    g[z*128+t] = 1.0f/(1.0f + __expf(-o));
  }
}

// ---------------- combiner: LDS-tiled 1x1 conv — outs read ONCE ----------------
__global__ __launch_bounds__(256) void combiner(const float* __restrict__ outs,
                                                const float* __restrict__ g,
                                                const float* __restrict__ Wc,
                                                const float* __restrict__ bc,
                                                float* __restrict__ out){
  __shared__ float sc[128][33];
  const int z = blockIdx.y, q0 = blockIdx.x*32, t = threadIdx.x;
  const float* gz = g + z*128;
  #pragma unroll
  for(int it=0; it<4; ++it){
    const int qi = it*8 + (t>>5);
    const int c4 = (t&31)*4;
    const float4 v = *(const float4*)(outs + ((size_t)z*L + q0 + qi)*128 + c4);
    sc[c4+0][qi] = v.x*gz[c4+0];
    sc[c4+1][qi] = v.y*gz[c4+1];
    sc[c4+2][qi] = v.z*gz[c4+2];
    sc[c4+3][qi] = v.w*gz[c4+3];
  }
  __syncthreads();
  const int qi = t & 31, ob = t >> 5;
  float acc[8];
  #pragma unroll
  for(int k=0;k<8;k++) acc[k] = bc[ob*8+k];
  for(int ch=0; ch<128; ++ch){
    const float v = sc[ch][qi];
    #pragma unroll
    for(int k=0;k<8;k++)
      acc[k] = fmaf(v, Wc[(size_t)(ob*8+k)*128 + ch], acc[k]);
  }
  #pragma unroll
  for(int k=0;k<8;k++){
    const int o = ob*8 + k;
    out[((size_t)z*64 + o)*L + q0 + qi] = acc[k];
  }
}

extern "C" void kernel_launch(void* const* d_in, const int* in_sizes, int n_in,
                              void* d_out, int out_size, void* d_ws, size_t ws_size,
                              hipStream_t stream){
  const float* fg   = (const float*)d_in[0];
  const float* mask = (const float*)d_in[1];
  const float* W1   = (const float*)d_in[2];
  const float* b1   = (const float*)d_in[3];
  const float* W2   = (const float*)d_in[4];
  const float* b2   = (const float*)d_in[5];
  const float* Wc   = (const float*)d_in[6];
  const float* bc   = (const float*)d_in[7];
  float* out = (float*)d_out;

  char* w = (char*)d_ws;
  size_t off = 0;
  auto alloc = [&](size_t bytes)->void*{
    void* p = (void*)(w + off);
    off += (bytes + 255) & ~(size_t)255;
    return p;
  };
  _Float16* S    = (_Float16*)alloc(2ull*L*L*2);   // p3 scores / A''
  _Float16* DxB  = (_Float16*)alloc(2ull*L*L*2);   // d9 output G
  _Float16* Cp16 = (_Float16*)alloc(8ull*2*L*64*2); // fp16 split-K partials (N=64)
  float* outs  = (float*)alloc(2ull*L*128*4);
  float* fgT   = (float*)alloc(2ull*L*64*4);
  _Float16* BhatH1 = (_Float16*)alloc(2ull*L*64*2);
  _Float16* BhatT1 = (_Float16*)alloc(2ull*64*L*2);
  _Float16* PfgH1  = (_Float16*)alloc(2ull*L*64*2);
  _Float16* BhatH3 = (_Float16*)alloc(2ull*L*D3*2);
  _Float16* PfgH3  = (_Float16*)alloc(2ull*L*D3*2);
  _Float16* bgH    = (_Float16*)alloc(2ull*64*L*2);
  _Float16* Opb = (_Float16*)alloc((size_t)32*L*64*2);  // raw fp16 flash partials
  float* Mlb  = (float*)alloc((size_t)32*L*4);
  float* Llb  = (float*)alloc((size_t)32*L*4);
  float* rn3v = (float*)alloc(2ull*L*4);
  float* Tq   = (float*)alloc(2ull*L*4);
  float* part = (float*)alloc(2ull*1024*128*4);
  float* gbuf = (float*)alloc(1024);
  const size_t sPart = 2ull*L*64;   // elements per split (fp16, N=64)

  // ================= prep (fused transpose + bgH) =================
  prep_fg<<<dim3(64,2),256,0,stream>>>(fg, mask, fgT, bgH);
  build_all<<<dim3(L/4,2),256,0,stream>>>(fgT, mask, BhatH1, PfgH1, BhatH3, PfgH3, rn3v);
  transpose_h<<<dim3(1,64,2),256,0,stream>>>((const ushort*)BhatH1, (ushort*)BhatT1,
                                             64, (size_t)L*64, (size_t)64*L);

  // ================= p=1 branch (barrier-free flash, 16-way split) =================
  flash_p1<<<dim3(L/QB,NSPLIT,2),256,0,stream>>>(PfgH1, BhatH1, BhatT1, Opb, Mlb, Llb);

  // ================= p=3 branch =================
  gemm_h16<2,1><<<dim3(32,32,2),256,0,stream>>>(
      PfgH3, D3, (size_t)L*D3,
      BhatH3, D3, (size_t)L*D3,
      (void*)S, L, (size_t)L*L, D3, 0);
  softmax_rn<<<dim3(L,2),256,0,stream>>>(S, rn3v, Tq);
  d9_pass<<<dim3(L/2,4),256,0,stream>>>(S, DxB);
  gemm_pv64<<<dim3(1,32,16),256,0,stream>>>(DxB, bgH, Cp16, sPart);

  // ================= fused epilogue (both branches + SE partials) =================
  epilogue_qc<<<dim3(L/4,2),256,0,stream>>>(Opb, Mlb, Llb, Cp16, Tq, fgT, mask,
                                            outs, part, sPart);

  // ================= SE + combiner =================
  se_mlp<<<2,512,0,stream>>>(part, W1, b1, W2, b2, gbuf);
  combiner<<<dim3(L/32,2),256,0,stream>>>(outs, gbuf, Wc, bc, out);
}